// Round 1
// baseline (1247.002 us; speedup 1.0000x reference)
//
#include <hip/hip_runtime.h>

#define NODES 50000
#define EDGES 800000

__device__ __forceinline__ float elu1(float x) { return x > 0.f ? x : expm1f(x); }

// ---------------- CSR build ----------------
__global__ __launch_bounds__(256) void k_hist(const int* __restrict__ ei, int* __restrict__ deg) {
  int e = blockIdx.x * 256 + threadIdx.x;
  if (e < EDGES) atomicAdd(deg + ei[e * 3 + 1], 1);
}

__global__ __launch_bounds__(512) void k_scan1(const int* __restrict__ deg, int* __restrict__ offs,
                                               int* __restrict__ bsum) {
  __shared__ int s[512];
  int t = threadIdx.x, i = blockIdx.x * 512 + t;
  int v = (i < NODES) ? deg[i] : 0;
  s[t] = v;
  __syncthreads();
  for (int o = 1; o < 512; o <<= 1) {
    int x = (t >= o) ? s[t - o] : 0;
    __syncthreads();
    s[t] += x;
    __syncthreads();
  }
  if (i < NODES) offs[i] = s[t] - v;  // exclusive within block
  if (t == 511) bsum[blockIdx.x] = s[511];
}

__global__ __launch_bounds__(128) void k_scan2(int* __restrict__ bsum, int nb) {
  __shared__ int s[128];
  int t = threadIdx.x;
  int v = (t < nb) ? bsum[t] : 0;
  s[t] = v;
  __syncthreads();
  for (int o = 1; o < 128; o <<= 1) {
    int x = (t >= o) ? s[t - o] : 0;
    __syncthreads();
    s[t] += x;
    __syncthreads();
  }
  if (t < nb) bsum[t] = s[t] - v;
}

__global__ __launch_bounds__(512) void k_scan3(int* __restrict__ offs, const int* __restrict__ bsum,
                                               int* __restrict__ cursor) {
  int i = blockIdx.x * 512 + threadIdx.x;
  if (i < NODES) {
    int v = offs[i] + bsum[blockIdx.x];
    offs[i] = v;
    cursor[i] = v;
  }
  if (i == 0) offs[NODES] = EDGES;
}

__global__ __launch_bounds__(256) void k_scatter(const int* __restrict__ ei, int* __restrict__ cursor,
                                                 unsigned* __restrict__ perm) {
  int e = blockIdx.x * 256 + threadIdx.x;
  if (e >= EDGES) return;
  int src = ei[e * 3 + 0];
  int tgt = ei[e * 3 + 1];
  int sg  = ei[e * 3 + 2];
  int p = atomicAdd(cursor + tgt, 1);
  perm[p] = (unsigned)src | (sg < 0 ? 0x80000000u : 0u);
}

// ---------------- y = x @ {Wp,Wn,Ws}.T  (out dim 32, K = 32 or 64) ----------------
template <int K>
__global__ __launch_bounds__(256) void k_lin(const float* __restrict__ x,
    const float* __restrict__ Wp, const float* __restrict__ Wn, const float* __restrict__ Ws,
    float* __restrict__ yp, float* __restrict__ yn, float* __restrict__ ys) {
  __shared__ float wpT[K * 32], wnT[K * 32], wsT[K * 32];
  __shared__ float xs[8][K];
  for (int i = threadIdx.x; i < 32 * K; i += 256) {
    int c = i / K, k = i % K;                 // W is (32, K) row-major; store transposed
    wpT[k * 32 + c] = Wp[i];
    wnT[k * 32 + c] = Wn[i];
    wsT[k * 32 + c] = Ws[i];
  }
  int base = blockIdx.x * 8;                  // NODES % 8 == 0, grid = NODES/8
  for (int i = threadIdx.x; i < 8 * K; i += 256) {
    int r = i / K, c = i % K;
    xs[r][c] = x[(base + r) * K + c];
  }
  __syncthreads();
  int lane = threadIdx.x & 31, local = threadIdx.x >> 5;
  int node = base + local;
  float ap = 0.f, an = 0.f, as = 0.f;
#pragma unroll
  for (int k = 0; k < K; k++) {
    float xv = xs[local][k];                  // broadcast (conflict-free)
    ap = fmaf(xv, wpT[k * 32 + lane], ap);    // bank = lane (conflict-free)
    an = fmaf(xv, wnT[k * 32 + lane], an);
    as = fmaf(xv, wsT[k * 32 + lane], as);
  }
  yp[node * 32 + lane] = ap;
  yn[node * 32 + lane] = an;
  ys[node * 32 + lane] = as;
}

// ---------------- aggregation: z[t] = ELU(ys[t] + sum_in y_{sign}[src]) (+ 0.1*zprev) ----------------
__global__ __launch_bounds__(256) void k_agg(const float* __restrict__ yp, const float* __restrict__ yn,
    const float* __restrict__ ys, const unsigned* __restrict__ perm, const int* __restrict__ offs,
    const float* __restrict__ zprev, float* __restrict__ zout) {
  int lane = threadIdx.x & 31;
  int node = blockIdx.x * 8 + (threadIdx.x >> 5);
  int beg = offs[node], end = offs[node + 1];
  float acc = ys[node * 32 + lane];
  int n = end - beg;
  for (int b = 0; b < n; b += 32) {
    unsigned pe = (b + lane < n) ? perm[beg + b + lane] : 0u;  // coalesced chunk load
    int lim = min(32, n - b);
    for (int j = 0; j < lim; j++) {
      unsigned ss = __shfl(pe, j, 32);
      const float* yb = (ss & 0x80000000u) ? yn : yp;          // uniform per 32-group
      acc += yb[(ss & 0x7FFFFFFFu) * 32 + lane];               // 128B coalesced gather
    }
  }
  float v = elu1(acc);
  if (zprev) v += 0.1f * zprev[node * 32 + lane];
  zout[node * 32 + lane] = v;
}

// ---------------- ASFR ----------------
__global__ __launch_bounds__(256) void k_asfr(const float* __restrict__ z,
    const float* __restrict__ lnw, const float* __restrict__ lnb,
    const float* __restrict__ gw, const float* __restrict__ gb, float* __restrict__ out) {
  __shared__ float gwT[32 * 32];
  __shared__ float xb[8][32];
  for (int i = threadIdx.x; i < 1024; i += 256) {
    int c = i >> 5, k = i & 31;
    gwT[k * 32 + c] = gw[i];
  }
  int lane = threadIdx.x & 31, local = threadIdx.x >> 5;
  int node = blockIdx.x * 8 + local;
  __syncthreads();
  float v = z[node * 32 + lane];
  float s = v;
#pragma unroll
  for (int m = 16; m; m >>= 1) s += __shfl_xor(s, m, 32);
  float mu = s * (1.f / 32.f);
  float d = v - mu, sq = d * d;
#pragma unroll
  for (int m = 16; m; m >>= 1) sq += __shfl_xor(sq, m, 32);
  float xn = d * rsqrtf(sq * (1.f / 32.f) + 1e-5f) * lnw[lane] + lnb[lane];
  xb[local][lane] = xn;
  __syncthreads();
  float a = gb[lane];
#pragma unroll
  for (int j = 0; j < 32; j++) a = fmaf(xb[local][j], gwT[j * 32 + lane], a);
  float g = 1.f / (1.f + __expf(-a));
  float w1 = g > 0.5f ? 1.f : g;
  float w2 = g > 0.5f ? 0.f : g;
  float x1 = w1 * v, x2 = w2 * v;
  // out[:, :16] = x1[:, :16] + x2[:, 16:]; out[:, 16:] = x1[:, 16:] + x2[:, :16]
  out[node * 32 + lane] = x1 + __shfl_xor(x2, 16, 32);
}

// ---------------- fused head: proj + ELU -> out z; MLP(LN,ReLU)x2 -> sigmoid prob ----------------
__global__ __launch_bounds__(256) void k_mlp(const float* __restrict__ z,
    const float* __restrict__ pw, const float* __restrict__ pb,
    const float* __restrict__ w1, const float* __restrict__ b1,
    const float* __restrict__ l1w, const float* __restrict__ l1b,
    const float* __restrict__ w2, const float* __restrict__ b2,
    const float* __restrict__ l2w, const float* __restrict__ l2b,
    const float* __restrict__ w3, const float* __restrict__ b3,
    float* __restrict__ outz, float* __restrict__ outp) {
  __shared__ float pT[32 * 64];
  __shared__ float w1T[64 * 64];
  __shared__ float w2T[64 * 64];
  for (int i = threadIdx.x; i < 64 * 32; i += 256) {
    int c = i >> 5, k = i & 31;
    pT[k * 64 + c] = pw[i];                   // pw is (64,32)
  }
  for (int i = threadIdx.x; i < 64 * 64; i += 256) {
    int c = i >> 6, k = i & 63;
    w1T[k * 64 + c] = w1[i];
    w2T[k * 64 + c] = w2[i];
  }
  __syncthreads();
  int lane = threadIdx.x & 63;
  int node = blockIdx.x * 4 + (threadIdx.x >> 6);   // grid = NODES/4
  float zv = (lane < 32) ? z[node * 32 + lane] : 0.f;
  float a = pb[lane];
#pragma unroll
  for (int j = 0; j < 32; j++) a = fmaf(__shfl(zv, j, 64), pT[j * 64 + lane], a);
  float z64 = elu1(a);
  outz[node * 64 + lane] = z64;
  // layer 1: GEMV + LN + ReLU
  float h = b1[lane];
#pragma unroll
  for (int j = 0; j < 64; j++) h = fmaf(__shfl(z64, j, 64), w1T[j * 64 + lane], h);
  float s = h;
#pragma unroll
  for (int m = 32; m; m >>= 1) s += __shfl_xor(s, m, 64);
  float mu = s * (1.f / 64.f);
  float d = h - mu, sq = d * d;
#pragma unroll
  for (int m = 32; m; m >>= 1) sq += __shfl_xor(sq, m, 64);
  float h1 = d * rsqrtf(sq * (1.f / 64.f) + 1e-5f) * l1w[lane] + l1b[lane];
  h1 = fmaxf(h1, 0.f);
  // layer 2
  float h2 = b2[lane];
#pragma unroll
  for (int j = 0; j < 64; j++) h2 = fmaf(__shfl(h1, j, 64), w2T[j * 64 + lane], h2);
  s = h2;
#pragma unroll
  for (int m = 32; m; m >>= 1) s += __shfl_xor(s, m, 64);
  mu = s * (1.f / 64.f);
  d = h2 - mu; sq = d * d;
#pragma unroll
  for (int m = 32; m; m >>= 1) sq += __shfl_xor(sq, m, 64);
  float hh = d * rsqrtf(sq * (1.f / 64.f) + 1e-5f) * l2w[lane] + l2b[lane];
  hh = fmaxf(hh, 0.f);
  // final dot + sigmoid
  float p = hh * w3[lane];
#pragma unroll
  for (int m = 32; m; m >>= 1) p += __shfl_xor(p, m, 64);
  if (lane == 0) outp[node] = 1.f / (1.f + __expf(-(p + b3[0])));
}

extern "C" void kernel_launch(void* const* d_in, const int* in_sizes, int n_in,
                              void* d_out, int out_size, void* d_ws, size_t ws_size,
                              hipStream_t stream) {
  const float* init_emb = (const float*)d_in[0];
  const int*   ei  = (const int*)d_in[1];
  const float* W1p = (const float*)d_in[2];
  const float* W1n = (const float*)d_in[3];
  const float* W1s = (const float*)d_in[4];
  const float* Wlp = (const float*)d_in[5];
  const float* Wln = (const float*)d_in[6];
  const float* Wls = (const float*)d_in[7];
  const float* lnw = (const float*)d_in[8];
  const float* lnb = (const float*)d_in[9];
  const float* gw  = (const float*)d_in[10];
  const float* gb  = (const float*)d_in[11];
  const float* pw  = (const float*)d_in[12];
  const float* pb  = (const float*)d_in[13];
  const float* w1  = (const float*)d_in[14];
  const float* b1  = (const float*)d_in[15];
  const float* l1w = (const float*)d_in[16];
  const float* l1b = (const float*)d_in[17];
  const float* w2  = (const float*)d_in[18];
  const float* b2  = (const float*)d_in[19];
  const float* l2w = (const float*)d_in[20];
  const float* l2b = (const float*)d_in[21];
  const float* w3  = (const float*)d_in[22];
  const float* b3  = (const float*)d_in[23];

  char* ws = (char*)d_ws;
  size_t off = 0;
  auto alloc = [&](size_t b) { void* p = ws + off; off = (off + b + 255) & ~(size_t)255; return p; };
  float*    ypos   = (float*)alloc(NODES * 32 * 4);
  float*    yneg   = (float*)alloc(NODES * 32 * 4);
  float*    ysel   = (float*)alloc(NODES * 32 * 4);
  float*    zA     = (float*)alloc(NODES * 32 * 4);
  float*    zB     = (float*)alloc(NODES * 32 * 4);
  unsigned* perm   = (unsigned*)alloc(EDGES * 4);
  int*      deg    = (int*)alloc(NODES * 4);
  int*      offs   = (int*)alloc((NODES + 1) * 4);
  int*      cursor = (int*)alloc(NODES * 4);
  int*      bsum   = (int*)alloc(128 * 4);

  // ---- CSR build (once per launch) ----
  hipMemsetAsync(deg, 0, NODES * 4, stream);
  k_hist<<<(EDGES + 255) / 256, 256, 0, stream>>>(ei, deg);
  int nb = (NODES + 511) / 512;  // 98
  k_scan1<<<nb, 512, 0, stream>>>(deg, offs, bsum);
  k_scan2<<<1, 128, 0, stream>>>(bsum, nb);
  k_scan3<<<nb, 512, 0, stream>>>(offs, bsum, cursor);
  k_scatter<<<(EDGES + 255) / 256, 256, 0, stream>>>(ei, cursor, perm);

  // ---- layer 1 (K=64) + ASFR ----
  k_lin<64><<<NODES / 8, 256, 0, stream>>>(init_emb, W1p, W1n, W1s, ypos, yneg, ysel);
  k_agg<<<NODES / 8, 256, 0, stream>>>(ypos, yneg, ysel, perm, offs, nullptr, zA);
  k_asfr<<<NODES / 8, 256, 0, stream>>>(zA, lnw, lnb, gw, gb, zB);

  // ---- layers 2..9 (K=32), residual from i>=1 ----
  float* zcur = zB;
  float* znxt = zA;
  for (int i = 0; i < 8; i++) {
    k_lin<32><<<NODES / 8, 256, 0, stream>>>(zcur, Wlp + i * 1024, Wln + i * 1024, Wls + i * 1024,
                                             ypos, yneg, ysel);
    k_agg<<<NODES / 8, 256, 0, stream>>>(ypos, yneg, ysel, perm, offs,
                                         (i > 0) ? zcur : nullptr, znxt);
    float* t = zcur; zcur = znxt; znxt = t;
  }

  // ---- fused head ----
  float* outz = (float*)d_out;
  float* outp = outz + (size_t)NODES * 64;
  k_mlp<<<NODES / 4, 256, 0, stream>>>(zcur, pw, pb, w1, b1, l1w, l1b,
                                       w2, b2, l2w, l2b, w3, b3, outz, outp);
}

// Round 2
// 550.826 us; speedup vs baseline: 2.2639x; 2.2639x over previous
//
#include <hip/hip_runtime.h>

#define NODES 50000
#define EDGES 800000

__device__ __forceinline__ float elu1(float x) { return x > 0.f ? x : expm1f(x); }

// ---------------- CSR build ----------------
__global__ __launch_bounds__(256) void k_hist(const int* __restrict__ ei, int* __restrict__ deg) {
  int e = blockIdx.x * 256 + threadIdx.x;
  if (e < EDGES) atomicAdd(deg + ei[e * 3 + 1], 1);
}

__global__ __launch_bounds__(512) void k_scan1(const int* __restrict__ deg, int* __restrict__ offs,
                                               int* __restrict__ bsum) {
  __shared__ int s[512];
  int t = threadIdx.x, i = blockIdx.x * 512 + t;
  int v = (i < NODES) ? deg[i] : 0;
  s[t] = v;
  __syncthreads();
  for (int o = 1; o < 512; o <<= 1) {
    int x = (t >= o) ? s[t - o] : 0;
    __syncthreads();
    s[t] += x;
    __syncthreads();
  }
  if (i < NODES) offs[i] = s[t] - v;
  if (t == 511) bsum[blockIdx.x] = s[511];
}

__global__ __launch_bounds__(128) void k_scan2(int* __restrict__ bsum, int nb) {
  __shared__ int s[128];
  int t = threadIdx.x;
  int v = (t < nb) ? bsum[t] : 0;
  s[t] = v;
  __syncthreads();
  for (int o = 1; o < 128; o <<= 1) {
    int x = (t >= o) ? s[t - o] : 0;
    __syncthreads();
    s[t] += x;
    __syncthreads();
  }
  if (t < nb) bsum[t] = s[t] - v;
}

__global__ __launch_bounds__(512) void k_scan3(int* __restrict__ offs, const int* __restrict__ bsum,
                                               int* __restrict__ cursor) {
  int i = blockIdx.x * 512 + threadIdx.x;
  if (i < NODES) {
    int v = offs[i] + bsum[blockIdx.x];
    offs[i] = v;
    cursor[i] = v;
  }
  if (i == 0) offs[NODES] = EDGES;
}

__global__ __launch_bounds__(256) void k_scatter(const int* __restrict__ ei, int* __restrict__ cursor,
                                                 unsigned* __restrict__ perm) {
  int e = blockIdx.x * 256 + threadIdx.x;
  if (e >= EDGES) return;
  int src = ei[e * 3 + 0];
  int tgt = ei[e * 3 + 1];
  int sg  = ei[e * 3 + 2];
  int p = atomicAdd(cursor + tgt, 1);
  perm[p] = (unsigned)src | (sg < 0 ? 0x80000000u : 0u);
}

// ---------------- y = x @ {Wp,Wn,Ws}.T (out 32, K=32/64), float4 LDS ----------------
template <int K>
__global__ __launch_bounds__(256) void k_lin(const float* __restrict__ x,
    const float* __restrict__ Wp, const float* __restrict__ Wn, const float* __restrict__ Ws,
    float* __restrict__ yp, float* __restrict__ yn, float* __restrict__ ys) {
  constexpr int K4 = K / 4;
  __shared__ float4 wp4[32][K4 + 1], wn4[32][K4 + 1], ws4[32][K4 + 1];  // padded rows
  __shared__ float4 xs4[8][K4];
  for (int i = threadIdx.x; i < 32 * K4; i += 256) {
    int c = i / K4, k4 = i - c * K4;
    wp4[c][k4] = ((const float4*)Wp)[i];
    wn4[c][k4] = ((const float4*)Wn)[i];
    ws4[c][k4] = ((const float4*)Ws)[i];
  }
  int base = blockIdx.x * 8;
  for (int i = threadIdx.x; i < 8 * K4; i += 256) {
    int r = i / K4, k4 = i - r * K4;
    xs4[r][k4] = ((const float4*)(x + (size_t)(base + r) * K))[k4];
  }
  __syncthreads();
  int lane = threadIdx.x & 31, local = threadIdx.x >> 5;
  float ap = 0.f, an = 0.f, asf = 0.f;
#pragma unroll
  for (int k4 = 0; k4 < K4; k4++) {
    float4 xv = xs4[local][k4];
    float4 a = wp4[lane][k4], b = wn4[lane][k4], c = ws4[lane][k4];
    ap  = fmaf(xv.w, a.w, fmaf(xv.z, a.z, fmaf(xv.y, a.y, fmaf(xv.x, a.x, ap))));
    an  = fmaf(xv.w, b.w, fmaf(xv.z, b.z, fmaf(xv.y, b.y, fmaf(xv.x, b.x, an))));
    asf = fmaf(xv.w, c.w, fmaf(xv.z, c.z, fmaf(xv.y, c.y, fmaf(xv.x, c.x, asf))));
  }
  size_t o = (size_t)(base + local) * 32 + lane;
  yp[o] = ap; yn[o] = an; ys[o] = asf;
}

// ---------------- aggregation: 4 edges in flight, float4 per lane ----------------
__global__ __launch_bounds__(256) void k_agg(const float* __restrict__ yp, const float* __restrict__ yn,
    const float* __restrict__ ys, const unsigned* __restrict__ perm, const int* __restrict__ offs,
    const float* __restrict__ zres, float* __restrict__ zout) {
  int lane = threadIdx.x & 31;
  int node = blockIdx.x * 8 + (threadIdx.x >> 5);
  int es = lane >> 3, fs = lane & 7;  // edge-slot 0..3, float4-slot 0..7
  int beg = offs[node], end = offs[node + 1];
  float4 acc = make_float4(0.f, 0.f, 0.f, 0.f);
#pragma unroll 2
  for (int b = beg + es; b < end; b += 4) {
    unsigned u = perm[b];
    const float* yb = (u & 0x80000000u) ? yn : yp;
    float4 v = *(const float4*)(yb + ((size_t)(u & 0x7FFFFFFFu) * 32 + fs * 4));
    acc.x += v.x; acc.y += v.y; acc.z += v.z; acc.w += v.w;
  }
#pragma unroll
  for (int m = 8; m <= 16; m <<= 1) {
    acc.x += __shfl_xor(acc.x, m, 32);
    acc.y += __shfl_xor(acc.y, m, 32);
    acc.z += __shfl_xor(acc.z, m, 32);
    acc.w += __shfl_xor(acc.w, m, 32);
  }
  if (es == 0) {
    float4 sv = *(const float4*)(ys + (size_t)node * 32 + fs * 4);
    float4 z;
    z.x = elu1(acc.x + sv.x); z.y = elu1(acc.y + sv.y);
    z.z = elu1(acc.z + sv.z); z.w = elu1(acc.w + sv.w);
    if (zres) {
      float4 r = *(const float4*)(zres + (size_t)node * 32 + fs * 4);
      z.x += 0.1f * r.x; z.y += 0.1f * r.y; z.z += 0.1f * r.z; z.w += 0.1f * r.w;
    }
    *(float4*)(zout + (size_t)node * 32 + fs * 4) = z;
  }
}

// ---------------- ASFR fused with the following k_lin (Wl[0]) ----------------
__global__ __launch_bounds__(256) void k_asfr_lin(const float* __restrict__ z,
    const float* __restrict__ lnw, const float* __restrict__ lnb,
    const float* __restrict__ gw, const float* __restrict__ gb,
    const float* __restrict__ Wp, const float* __restrict__ Wn, const float* __restrict__ Ws,
    float* __restrict__ yp, float* __restrict__ yn, float* __restrict__ ys) {
  __shared__ float4 gw4[32][9], wp4[32][9], wn4[32][9], ws4[32][9];
  __shared__ float sb[8][36];
  {
    int i = threadIdx.x;  // exactly 256 float4 per matrix
    int c = i >> 3, k4 = i & 7;
    gw4[c][k4] = ((const float4*)gw)[i];
    wp4[c][k4] = ((const float4*)Wp)[i];
    wn4[c][k4] = ((const float4*)Wn)[i];
    ws4[c][k4] = ((const float4*)Ws)[i];
  }
  int lane = threadIdx.x & 31, local = threadIdx.x >> 5;
  int node = blockIdx.x * 8 + local;
  float v = z[(size_t)node * 32 + lane];
  float s = v;
#pragma unroll
  for (int m = 16; m; m >>= 1) s += __shfl_xor(s, m, 32);
  float mu = s * (1.f / 32.f);
  float d = v - mu, sq = d * d;
#pragma unroll
  for (int m = 16; m; m >>= 1) sq += __shfl_xor(sq, m, 32);
  float xn = d * rsqrtf(sq * (1.f / 32.f) + 1e-5f) * lnw[lane] + lnb[lane];
  sb[local][lane] = xn;
  __syncthreads();
  float a = gb[lane];
#pragma unroll
  for (int k4 = 0; k4 < 8; k4++) {
    float4 xv = *((const float4*)&sb[local][0] + k4);
    float4 w = gw4[lane][k4];
    a = fmaf(xv.w, w.w, fmaf(xv.z, w.z, fmaf(xv.y, w.y, fmaf(xv.x, w.x, a))));
  }
  float g = 1.f / (1.f + __expf(-a));
  float w1 = g > 0.5f ? 1.f : g;
  float w2 = g > 0.5f ? 0.f : g;
  float zn = w1 * v + __shfl_xor(w2 * v, 16, 32);
  __syncthreads();
  sb[local][lane] = zn;
  __syncthreads();
  float ap = 0.f, an = 0.f, asf = 0.f;
#pragma unroll
  for (int k4 = 0; k4 < 8; k4++) {
    float4 xv = *((const float4*)&sb[local][0] + k4);
    float4 a2 = wp4[lane][k4], b2 = wn4[lane][k4], c2 = ws4[lane][k4];
    ap  = fmaf(xv.w, a2.w, fmaf(xv.z, a2.z, fmaf(xv.y, a2.y, fmaf(xv.x, a2.x, ap))));
    an  = fmaf(xv.w, b2.w, fmaf(xv.z, b2.z, fmaf(xv.y, b2.y, fmaf(xv.x, b2.x, an))));
    asf = fmaf(xv.w, c2.w, fmaf(xv.z, c2.z, fmaf(xv.y, c2.y, fmaf(xv.x, c2.x, asf))));
  }
  size_t o = (size_t)node * 32 + lane;
  yp[o] = ap; yn[o] = an; ys[o] = asf;
}

// ---------------- head: thread-per-node, register-resident, LDS broadcast weights ----------------
__global__ __launch_bounds__(64) void k_mlp(const float* __restrict__ z,
    const float* __restrict__ pw, const float* __restrict__ pb,
    const float* __restrict__ w1, const float* __restrict__ b1,
    const float* __restrict__ l1w, const float* __restrict__ l1b,
    const float* __restrict__ w2, const float* __restrict__ b2,
    const float* __restrict__ l2w, const float* __restrict__ l2b,
    const float* __restrict__ w3, const float* __restrict__ b3,
    float* __restrict__ outz, float* __restrict__ outp) {
  __shared__ float4 pw4[512];
  __shared__ float4 w14[1024], w24[1024];
  __shared__ float pb_s[64], b1_s[64], l1w_s[64], l1b_s[64], b2_s[64], l2w_s[64], l2b_s[64], w3_s[64];
  int t = threadIdx.x;
  for (int i = t; i < 512; i += 64) pw4[i] = ((const float4*)pw)[i];
  for (int i = t; i < 1024; i += 64) { w14[i] = ((const float4*)w1)[i]; w24[i] = ((const float4*)w2)[i]; }
  pb_s[t] = pb[t]; b1_s[t] = b1[t]; l1w_s[t] = l1w[t]; l1b_s[t] = l1b[t];
  b2_s[t] = b2[t]; l2w_s[t] = l2w[t]; l2b_s[t] = l2b[t]; w3_s[t] = w3[t];
  __syncthreads();
  int node = blockIdx.x * 64 + t;
  if (node >= NODES) return;
  float x[32];
#pragma unroll
  for (int k4 = 0; k4 < 8; k4++) {
    float4 v = ((const float4*)(z + (size_t)node * 32))[k4];
    x[k4 * 4] = v.x; x[k4 * 4 + 1] = v.y; x[k4 * 4 + 2] = v.z; x[k4 * 4 + 3] = v.w;
  }
  float h[64];
#pragma unroll
  for (int j = 0; j < 64; j++) {
    float acc = pb_s[j];
#pragma unroll
    for (int k4 = 0; k4 < 8; k4++) {
      float4 w = pw4[j * 8 + k4];
      acc = fmaf(x[k4*4+3], w.w, fmaf(x[k4*4+2], w.z, fmaf(x[k4*4+1], w.y, fmaf(x[k4*4], w.x, acc))));
    }
    h[j] = elu1(acc);
  }
#pragma unroll
  for (int j4 = 0; j4 < 16; j4++) {
    float4 v = make_float4(h[j4*4], h[j4*4+1], h[j4*4+2], h[j4*4+3]);
    ((float4*)(outz + (size_t)node * 64))[j4] = v;
  }
  float g[64];
#pragma unroll
  for (int j = 0; j < 64; j++) {
    float acc = b1_s[j];
#pragma unroll
    for (int k4 = 0; k4 < 16; k4++) {
      float4 w = w14[j * 16 + k4];
      acc = fmaf(h[k4*4+3], w.w, fmaf(h[k4*4+2], w.z, fmaf(h[k4*4+1], w.y, fmaf(h[k4*4], w.x, acc))));
    }
    g[j] = acc;
  }
  float s = 0.f;
#pragma unroll
  for (int j = 0; j < 64; j++) s += g[j];
  float mu = s * (1.f / 64.f);
  float vs = 0.f;
#pragma unroll
  for (int j = 0; j < 64; j++) { float dd = g[j] - mu; vs += dd * dd; }
  float rs = rsqrtf(vs * (1.f / 64.f) + 1e-5f);
#pragma unroll
  for (int j = 0; j < 64; j++) h[j] = fmaxf((g[j] - mu) * rs * l1w_s[j] + l1b_s[j], 0.f);
#pragma unroll
  for (int j = 0; j < 64; j++) {
    float acc = b2_s[j];
#pragma unroll
    for (int k4 = 0; k4 < 16; k4++) {
      float4 w = w24[j * 16 + k4];
      acc = fmaf(h[k4*4+3], w.w, fmaf(h[k4*4+2], w.z, fmaf(h[k4*4+1], w.y, fmaf(h[k4*4], w.x, acc))));
    }
    g[j] = acc;
  }
  s = 0.f;
#pragma unroll
  for (int j = 0; j < 64; j++) s += g[j];
  mu = s * (1.f / 64.f);
  vs = 0.f;
#pragma unroll
  for (int j = 0; j < 64; j++) { float dd = g[j] - mu; vs += dd * dd; }
  rs = rsqrtf(vs * (1.f / 64.f) + 1e-5f);
  float p = 0.f;
#pragma unroll
  for (int j = 0; j < 64; j++) {
    float hv = fmaxf((g[j] - mu) * rs * l2w_s[j] + l2b_s[j], 0.f);
    p = fmaf(hv, w3_s[j], p);
  }
  outp[node] = 1.f / (1.f + __expf(-(p + b3[0])));
}

extern "C" void kernel_launch(void* const* d_in, const int* in_sizes, int n_in,
                              void* d_out, int out_size, void* d_ws, size_t ws_size,
                              hipStream_t stream) {
  const float* init_emb = (const float*)d_in[0];
  const int*   ei  = (const int*)d_in[1];
  const float* W1p = (const float*)d_in[2];
  const float* W1n = (const float*)d_in[3];
  const float* W1s = (const float*)d_in[4];
  const float* Wlp = (const float*)d_in[5];
  const float* Wln = (const float*)d_in[6];
  const float* Wls = (const float*)d_in[7];
  const float* lnw = (const float*)d_in[8];
  const float* lnb = (const float*)d_in[9];
  const float* gw  = (const float*)d_in[10];
  const float* gb  = (const float*)d_in[11];
  const float* pw  = (const float*)d_in[12];
  const float* pb  = (const float*)d_in[13];
  const float* w1  = (const float*)d_in[14];
  const float* b1  = (const float*)d_in[15];
  const float* l1w = (const float*)d_in[16];
  const float* l1b = (const float*)d_in[17];
  const float* w2  = (const float*)d_in[18];
  const float* b2  = (const float*)d_in[19];
  const float* l2w = (const float*)d_in[20];
  const float* l2b = (const float*)d_in[21];
  const float* w3  = (const float*)d_in[22];
  const float* b3  = (const float*)d_in[23];

  char* ws = (char*)d_ws;
  size_t off = 0;
  auto alloc = [&](size_t b) { void* p = ws + off; off = (off + b + 255) & ~(size_t)255; return p; };
  float*    ypos   = (float*)alloc(NODES * 32 * 4);
  float*    yneg   = (float*)alloc(NODES * 32 * 4);
  float*    ysel   = (float*)alloc(NODES * 32 * 4);
  float*    zA     = (float*)alloc(NODES * 32 * 4);
  float*    zB     = (float*)alloc(NODES * 32 * 4);
  unsigned* perm   = (unsigned*)alloc(EDGES * 4);
  int*      deg    = (int*)alloc(NODES * 4);
  int*      offs   = (int*)alloc((NODES + 1) * 4);
  int*      cursor = (int*)alloc(NODES * 4);
  int*      bsum   = (int*)alloc(128 * 4);

  // ---- CSR build ----
  hipMemsetAsync(deg, 0, NODES * 4, stream);
  k_hist<<<(EDGES + 255) / 256, 256, 0, stream>>>(ei, deg);
  int nb = (NODES + 511) / 512;
  k_scan1<<<nb, 512, 0, stream>>>(deg, offs, bsum);
  k_scan2<<<1, 128, 0, stream>>>(bsum, nb);
  k_scan3<<<nb, 512, 0, stream>>>(offs, bsum, cursor);
  k_scatter<<<(EDGES + 255) / 256, 256, 0, stream>>>(ei, cursor, perm);

  // ---- layer 1 (K=64) + ASFR(+lin Wl[0]) ----
  k_lin<64><<<NODES / 8, 256, 0, stream>>>(init_emb, W1p, W1n, W1s, ypos, yneg, ysel);
  k_agg<<<NODES / 8, 256, 0, stream>>>(ypos, yneg, ysel, perm, offs, nullptr, zA);
  k_asfr_lin<<<NODES / 8, 256, 0, stream>>>(zA, lnw, lnb, gw, gb, Wlp, Wln, Wls, ypos, yneg, ysel);

  // ---- loop i=0..7: agg (with residual for i>0), then lin with Wl[i+1] ----
  float* zo = zB;
  float* zr = nullptr;
  for (int i = 0; i < 8; i++) {
    k_agg<<<NODES / 8, 256, 0, stream>>>(ypos, yneg, ysel, perm, offs, zr, zo);
    if (i < 7)
      k_lin<32><<<NODES / 8, 256, 0, stream>>>(zo, Wlp + (i + 1) * 1024, Wln + (i + 1) * 1024,
                                               Wls + (i + 1) * 1024, ypos, yneg, ysel);
    zr = zo;
    zo = (zo == zB) ? zA : zB;
  }

  // ---- fused head ----
  float* outz = (float*)d_out;
  float* outp = outz + (size_t)NODES * 64;
  k_mlp<<<(NODES + 63) / 64, 64, 0, stream>>>(zr, pw, pb, w1, b1, l1w, l1b,
                                              w2, b2, l2w, l2b, w3, b3, outz, outp);
}

// Round 3
// 479.172 us; speedup vs baseline: 2.6024x; 1.1495x over previous
//
#include <hip/hip_runtime.h>
#include <hip/hip_bf16.h>

#define NODES 50000
#define EDGES 800000

__device__ __forceinline__ float elu1(float x) { return x > 0.f ? x : expm1f(x); }

union F4 { float4 v; float f[4]; };

// ---------------- CSR build ----------------
__global__ __launch_bounds__(256) void k_hist(const int* __restrict__ ei, int* __restrict__ deg) {
  int e = blockIdx.x * 256 + threadIdx.x;
  if (e < EDGES) atomicAdd(deg + ei[e * 3 + 1], 1);
}

__global__ __launch_bounds__(512) void k_scan1(const int* __restrict__ deg, int* __restrict__ offs,
                                               int* __restrict__ bsum) {
  __shared__ int s[512];
  int t = threadIdx.x, i = blockIdx.x * 512 + t;
  int v = (i < NODES) ? deg[i] : 0;
  s[t] = v;
  __syncthreads();
  for (int o = 1; o < 512; o <<= 1) {
    int x = (t >= o) ? s[t - o] : 0;
    __syncthreads();
    s[t] += x;
    __syncthreads();
  }
  if (i < NODES) offs[i] = s[t] - v;
  if (t == 511) bsum[blockIdx.x] = s[511];
}

__global__ __launch_bounds__(128) void k_scan2(int* __restrict__ bsum, int nb) {
  __shared__ int s[128];
  int t = threadIdx.x;
  int v = (t < nb) ? bsum[t] : 0;
  s[t] = v;
  __syncthreads();
  for (int o = 1; o < 128; o <<= 1) {
    int x = (t >= o) ? s[t - o] : 0;
    __syncthreads();
    s[t] += x;
    __syncthreads();
  }
  if (t < nb) bsum[t] = s[t] - v;
}

__global__ __launch_bounds__(512) void k_scan3(int* __restrict__ offs, const int* __restrict__ bsum,
                                               int* __restrict__ cursor) {
  int i = blockIdx.x * 512 + threadIdx.x;
  if (i < NODES) {
    int v = offs[i] + bsum[blockIdx.x];
    offs[i] = v;
    cursor[i] = v;
  }
  if (i == 0) offs[NODES] = EDGES;
}

__global__ __launch_bounds__(256) void k_scatter(const int* __restrict__ ei, int* __restrict__ cursor,
                                                 unsigned* __restrict__ perm) {
  int e = blockIdx.x * 256 + threadIdx.x;
  if (e >= EDGES) return;
  int src = ei[e * 3 + 0];
  int tgt = ei[e * 3 + 1];
  int sg  = ei[e * 3 + 2];
  int p = atomicAdd(cursor + tgt, 1);
  perm[p] = (unsigned)src | (sg < 0 ? 0x80000000u : 0u);
}

// ---------------- y = x @ {Wp,Wn,Ws}.T (out 32, K=32/64); yp/yn bf16, ys fp32 ----------------
template <int K>
__global__ __launch_bounds__(256) void k_lin(const float* __restrict__ x,
    const float* __restrict__ Wp, const float* __restrict__ Wn, const float* __restrict__ Ws,
    __hip_bfloat16* __restrict__ ypb, __hip_bfloat16* __restrict__ ynb, float* __restrict__ ys) {
  constexpr int K4 = K / 4;
  __shared__ float4 wp[K4][32], wn[K4][32], wsm[K4][32];  // [k4][out-col]: contiguous reads
  __shared__ float4 xs[8][K4];
  for (int i = threadIdx.x; i < 32 * K4; i += 256) {
    int k4 = i >> 5, c = i & 31;
    wp[k4][c]  = ((const float4*)Wp)[c * K4 + k4];
    wn[k4][c]  = ((const float4*)Wn)[c * K4 + k4];
    wsm[k4][c] = ((const float4*)Ws)[c * K4 + k4];
  }
  int base = blockIdx.x * 8;
  for (int i = threadIdx.x; i < 8 * K4; i += 256) {
    int r = i / K4, k4 = i - r * K4;
    xs[r][k4] = ((const float4*)(x + (size_t)(base + r) * K))[k4];
  }
  __syncthreads();
  int lane = threadIdx.x & 31, local = threadIdx.x >> 5;
  float ap = 0.f, an = 0.f, asf = 0.f;
#pragma unroll
  for (int k4 = 0; k4 < K4; k4++) {
    float4 xv = xs[local][k4];
    float4 a = wp[k4][lane], b = wn[k4][lane], c = wsm[k4][lane];
    ap  = fmaf(xv.w, a.w, fmaf(xv.z, a.z, fmaf(xv.y, a.y, fmaf(xv.x, a.x, ap))));
    an  = fmaf(xv.w, b.w, fmaf(xv.z, b.z, fmaf(xv.y, b.y, fmaf(xv.x, b.x, an))));
    asf = fmaf(xv.w, c.w, fmaf(xv.z, c.z, fmaf(xv.y, c.y, fmaf(xv.x, c.x, asf))));
  }
  size_t o = (size_t)(base + local) * 32 + lane;
  ypb[o] = __float2bfloat16(ap);
  ynb[o] = __float2bfloat16(an);
  ys[o] = asf;
}

// ---------------- aggregation: 8 edges in flight, bf16 64B rows ----------------
__global__ __launch_bounds__(256) void k_agg(const unsigned short* __restrict__ ypb,
    const unsigned short* __restrict__ ynb, const float* __restrict__ ys,
    const unsigned* __restrict__ perm, const int* __restrict__ offs,
    const float* __restrict__ zres, float* __restrict__ zout) {
  int lane = threadIdx.x & 31;
  int node = blockIdx.x * 8 + (threadIdx.x >> 5);
  int es = lane >> 2, fs = lane & 3;  // edge-slot 0..7, 16B-slot 0..3 (8 bf16)
  int beg = offs[node], end = offs[node + 1];
  float a[8];
#pragma unroll
  for (int i = 0; i < 8; i++) a[i] = 0.f;
#pragma unroll 2
  for (int b = beg + es; b < end; b += 8) {
    unsigned u = perm[b];
    const unsigned short* base = (u >> 31) ? ynb : ypb;
    uint4 v = *((const uint4*)(base + (size_t)(u & 0x7FFFFFFFu) * 32) + fs);
    a[0] += __uint_as_float(v.x << 16);
    a[1] += __uint_as_float(v.x & 0xffff0000u);
    a[2] += __uint_as_float(v.y << 16);
    a[3] += __uint_as_float(v.y & 0xffff0000u);
    a[4] += __uint_as_float(v.z << 16);
    a[5] += __uint_as_float(v.z & 0xffff0000u);
    a[6] += __uint_as_float(v.w << 16);
    a[7] += __uint_as_float(v.w & 0xffff0000u);
  }
#pragma unroll
  for (int m = 4; m <= 16; m <<= 1) {
#pragma unroll
    for (int i = 0; i < 8; i++) a[i] += __shfl_xor(a[i], m, 32);
  }
  if (es == 0) {
    const float* ysr = ys + (size_t)node * 32 + fs * 8;
    F4 s0, s1;
    s0.v = *(const float4*)ysr;
    s1.v = *(const float4*)(ysr + 4);
    float o[8];
#pragma unroll
    for (int i = 0; i < 4; i++) o[i] = elu1(a[i] + s0.f[i]);
#pragma unroll
    for (int i = 0; i < 4; i++) o[4 + i] = elu1(a[4 + i] + s1.f[i]);
    if (zres) {
      const float* rr = zres + (size_t)node * 32 + fs * 8;
      F4 r0, r1;
      r0.v = *(const float4*)rr;
      r1.v = *(const float4*)(rr + 4);
#pragma unroll
      for (int i = 0; i < 4; i++) { o[i] += 0.1f * r0.f[i]; o[4 + i] += 0.1f * r1.f[i]; }
    }
    float* zr = zout + (size_t)node * 32 + fs * 8;
    *(float4*)zr = make_float4(o[0], o[1], o[2], o[3]);
    *(float4*)(zr + 4) = make_float4(o[4], o[5], o[6], o[7]);
  }
}

// ---------------- ASFR fused with lin(Wl[0]) ----------------
__global__ __launch_bounds__(256) void k_asfr_lin(const float* __restrict__ z,
    const float* __restrict__ lnw, const float* __restrict__ lnb,
    const float* __restrict__ gw, const float* __restrict__ gb,
    const float* __restrict__ Wp, const float* __restrict__ Wn, const float* __restrict__ Ws,
    __hip_bfloat16* __restrict__ ypb, __hip_bfloat16* __restrict__ ynb, float* __restrict__ ys) {
  __shared__ float4 gws[8][32], wps[8][32], wns[8][32], wss[8][32];
  __shared__ float sb[8][36], sb2[8][36];
  {
    int t = threadIdx.x;  // exactly 256 float4 per matrix
    int k4 = t >> 5, c = t & 31;
    gws[k4][c] = ((const float4*)gw)[c * 8 + k4];
    wps[k4][c] = ((const float4*)Wp)[c * 8 + k4];
    wns[k4][c] = ((const float4*)Wn)[c * 8 + k4];
    wss[k4][c] = ((const float4*)Ws)[c * 8 + k4];
  }
  int lane = threadIdx.x & 31, local = threadIdx.x >> 5;
  int node = blockIdx.x * 8 + local;
  float v = z[(size_t)node * 32 + lane];
  float s = v;
#pragma unroll
  for (int m = 16; m; m >>= 1) s += __shfl_xor(s, m, 32);
  float mu = s * (1.f / 32.f);
  float d = v - mu, sq = d * d;
#pragma unroll
  for (int m = 16; m; m >>= 1) sq += __shfl_xor(sq, m, 32);
  float xn = d * rsqrtf(sq * (1.f / 32.f) + 1e-5f) * lnw[lane] + lnb[lane];
  sb[local][lane] = xn;
  __syncthreads();
  float a = gb[lane];
#pragma unroll
  for (int k4 = 0; k4 < 8; k4++) {
    float4 xv = *((const float4*)&sb[local][0] + k4);
    float4 w = gws[k4][lane];
    a = fmaf(xv.w, w.w, fmaf(xv.z, w.z, fmaf(xv.y, w.y, fmaf(xv.x, w.x, a))));
  }
  float g = 1.f / (1.f + __expf(-a));
  float w1 = g > 0.5f ? 1.f : g;
  float w2 = g > 0.5f ? 0.f : g;
  float zn = w1 * v + __shfl_xor(w2 * v, 16, 32);
  sb2[local][lane] = zn;  // same wave: no barrier needed
  float ap = 0.f, an = 0.f, asf = 0.f;
#pragma unroll
  for (int k4 = 0; k4 < 8; k4++) {
    float4 xv = *((const float4*)&sb2[local][0] + k4);
    float4 a2 = wps[k4][lane], b2 = wns[k4][lane], c2 = wss[k4][lane];
    ap  = fmaf(xv.w, a2.w, fmaf(xv.z, a2.z, fmaf(xv.y, a2.y, fmaf(xv.x, a2.x, ap))));
    an  = fmaf(xv.w, b2.w, fmaf(xv.z, b2.z, fmaf(xv.y, b2.y, fmaf(xv.x, b2.x, an))));
    asf = fmaf(xv.w, c2.w, fmaf(xv.z, c2.z, fmaf(xv.y, c2.y, fmaf(xv.x, c2.x, asf))));
  }
  size_t o = (size_t)node * 32 + lane;
  ypb[o] = __float2bfloat16(ap);
  ynb[o] = __float2bfloat16(an);
  ys[o] = asf;
}

// ---------------- head: 4 lanes/node, rolled K-loops, LDS h-exchange ----------------
__global__ __launch_bounds__(256) void k_mlp(const float* __restrict__ z,
    const float* __restrict__ pw, const float* __restrict__ pb,
    const float* __restrict__ w1, const float* __restrict__ b1,
    const float* __restrict__ l1w, const float* __restrict__ l1b,
    const float* __restrict__ w2, const float* __restrict__ b2,
    const float* __restrict__ l2w, const float* __restrict__ l2b,
    const float* __restrict__ w3, const float* __restrict__ b3,
    float* __restrict__ outz, float* __restrict__ outp) {
  __shared__ float4 pT4[32 * 16];           // [k][j4]: proj weights transposed
  __shared__ float4 w1T4[64 * 16], w2T4[64 * 16];
  __shared__ float4 hbuf4[64 * 17];         // per-group row, padded for bank spread
  __shared__ float pb_s[64], b1_s[64], l1w_s[64], l1b_s[64], b2_s[64], l2w_s[64], l2b_s[64], w3_s[64];
  int t = threadIdx.x;
  for (int i = t; i < 512; i += 256) {
    int k = i >> 4, j4 = i & 15;
    float4 v;
    v.x = pw[(j4 * 4 + 0) * 32 + k]; v.y = pw[(j4 * 4 + 1) * 32 + k];
    v.z = pw[(j4 * 4 + 2) * 32 + k]; v.w = pw[(j4 * 4 + 3) * 32 + k];
    pT4[i] = v;
  }
  for (int i = t; i < 1024; i += 256) {
    int k = i >> 4, j4 = i & 15;
    float4 v, u;
    v.x = w1[(j4 * 4 + 0) * 64 + k]; v.y = w1[(j4 * 4 + 1) * 64 + k];
    v.z = w1[(j4 * 4 + 2) * 64 + k]; v.w = w1[(j4 * 4 + 3) * 64 + k];
    u.x = w2[(j4 * 4 + 0) * 64 + k]; u.y = w2[(j4 * 4 + 1) * 64 + k];
    u.z = w2[(j4 * 4 + 2) * 64 + k]; u.w = w2[(j4 * 4 + 3) * 64 + k];
    w1T4[i] = v; w2T4[i] = u;
  }
  if (t < 64) {
    pb_s[t] = pb[t]; b1_s[t] = b1[t]; l1w_s[t] = l1w[t]; l1b_s[t] = l1b[t];
    b2_s[t] = b2[t]; l2w_s[t] = l2w[t]; l2b_s[t] = l2b[t]; w3_s[t] = w3[t];
  }
  __syncthreads();
  int g = t >> 2, q = t & 3;
  int node = blockIdx.x * 64 + g;
  if (node >= NODES) return;
  float bb3 = b3[0];
  // stage z row into hbuf (within-wave: no barrier)
  {
    const float4* z4 = (const float4*)(z + (size_t)node * 32);
    hbuf4[g * 17 + q * 2 + 0] = z4[q * 2 + 0];
    hbuf4[g * 17 + q * 2 + 1] = z4[q * 2 + 1];
  }
  float acc[16], h[16];
#pragma unroll
  for (int i = 0; i < 16; i++) acc[i] = pb_s[q * 16 + i];
#pragma unroll 2
  for (int k4 = 0; k4 < 8; k4++) {
    F4 hv; hv.v = hbuf4[g * 17 + k4];
#pragma unroll
    for (int c = 0; c < 4; c++) {
      float hk = hv.f[c];
      const float4* wrow = &pT4[(k4 * 4 + c) * 16 + q * 4];
#pragma unroll
      for (int j4 = 0; j4 < 4; j4++) {
        float4 w = wrow[j4];
        acc[j4 * 4 + 0] = fmaf(hk, w.x, acc[j4 * 4 + 0]);
        acc[j4 * 4 + 1] = fmaf(hk, w.y, acc[j4 * 4 + 1]);
        acc[j4 * 4 + 2] = fmaf(hk, w.z, acc[j4 * 4 + 2]);
        acc[j4 * 4 + 3] = fmaf(hk, w.w, acc[j4 * 4 + 3]);
      }
    }
  }
#pragma unroll
  for (int i = 0; i < 16; i++) h[i] = elu1(acc[i]);
  {
    float4* oz = (float4*)(outz + (size_t)node * 64 + q * 16);
#pragma unroll
    for (int i4 = 0; i4 < 4; i4++)
      oz[i4] = make_float4(h[i4 * 4], h[i4 * 4 + 1], h[i4 * 4 + 2], h[i4 * 4 + 3]);
#pragma unroll
    for (int i4 = 0; i4 < 4; i4++)
      hbuf4[g * 17 + q * 4 + i4] = make_float4(h[i4 * 4], h[i4 * 4 + 1], h[i4 * 4 + 2], h[i4 * 4 + 3]);
  }
  // ---- layer 1 ----
#pragma unroll
  for (int i = 0; i < 16; i++) acc[i] = b1_s[q * 16 + i];
#pragma unroll 2
  for (int k4 = 0; k4 < 16; k4++) {
    F4 hv; hv.v = hbuf4[g * 17 + k4];
#pragma unroll
    for (int c = 0; c < 4; c++) {
      float hk = hv.f[c];
      const float4* wrow = &w1T4[(k4 * 4 + c) * 16 + q * 4];
#pragma unroll
      for (int j4 = 0; j4 < 4; j4++) {
        float4 w = wrow[j4];
        acc[j4 * 4 + 0] = fmaf(hk, w.x, acc[j4 * 4 + 0]);
        acc[j4 * 4 + 1] = fmaf(hk, w.y, acc[j4 * 4 + 1]);
        acc[j4 * 4 + 2] = fmaf(hk, w.z, acc[j4 * 4 + 2]);
        acc[j4 * 4 + 3] = fmaf(hk, w.w, acc[j4 * 4 + 3]);
      }
    }
  }
  {
    float s = 0.f;
#pragma unroll
    for (int i = 0; i < 16; i++) s += acc[i];
    s += __shfl_xor(s, 1, 4); s += __shfl_xor(s, 2, 4);
    float mu = s * (1.f / 64.f);
    float vs = 0.f;
#pragma unroll
    for (int i = 0; i < 16; i++) { float dd = acc[i] - mu; vs += dd * dd; }
    vs += __shfl_xor(vs, 1, 4); vs += __shfl_xor(vs, 2, 4);
    float rs = rsqrtf(vs * (1.f / 64.f) + 1e-5f);
#pragma unroll
    for (int i = 0; i < 16; i++)
      h[i] = fmaxf((acc[i] - mu) * rs * l1w_s[q * 16 + i] + l1b_s[q * 16 + i], 0.f);
  }
#pragma unroll
  for (int i4 = 0; i4 < 4; i4++)
    hbuf4[g * 17 + q * 4 + i4] = make_float4(h[i4 * 4], h[i4 * 4 + 1], h[i4 * 4 + 2], h[i4 * 4 + 3]);
  // ---- layer 2 ----
#pragma unroll
  for (int i = 0; i < 16; i++) acc[i] = b2_s[q * 16 + i];
#pragma unroll 2
  for (int k4 = 0; k4 < 16; k4++) {
    F4 hv; hv.v = hbuf4[g * 17 + k4];
#pragma unroll
    for (int c = 0; c < 4; c++) {
      float hk = hv.f[c];
      const float4* wrow = &w2T4[(k4 * 4 + c) * 16 + q * 4];
#pragma unroll
      for (int j4 = 0; j4 < 4; j4++) {
        float4 w = wrow[j4];
        acc[j4 * 4 + 0] = fmaf(hk, w.x, acc[j4 * 4 + 0]);
        acc[j4 * 4 + 1] = fmaf(hk, w.y, acc[j4 * 4 + 1]);
        acc[j4 * 4 + 2] = fmaf(hk, w.z, acc[j4 * 4 + 2]);
        acc[j4 * 4 + 3] = fmaf(hk, w.w, acc[j4 * 4 + 3]);
      }
    }
  }
  {
    float s = 0.f;
#pragma unroll
    for (int i = 0; i < 16; i++) s += acc[i];
    s += __shfl_xor(s, 1, 4); s += __shfl_xor(s, 2, 4);
    float mu = s * (1.f / 64.f);
    float vs = 0.f;
#pragma unroll
    for (int i = 0; i < 16; i++) { float dd = acc[i] - mu; vs += dd * dd; }
    vs += __shfl_xor(vs, 1, 4); vs += __shfl_xor(vs, 2, 4);
    float rs = rsqrtf(vs * (1.f / 64.f) + 1e-5f);
    float p = 0.f;
#pragma unroll
    for (int i = 0; i < 16; i++) {
      float hv2 = fmaxf((acc[i] - mu) * rs * l2w_s[q * 16 + i] + l2b_s[q * 16 + i], 0.f);
      p = fmaf(hv2, w3_s[q * 16 + i], p);
    }
    p += __shfl_xor(p, 1, 4); p += __shfl_xor(p, 2, 4);
    if (q == 0) outp[node] = 1.f / (1.f + __expf(-(p + bb3)));
  }
}

extern "C" void kernel_launch(void* const* d_in, const int* in_sizes, int n_in,
                              void* d_out, int out_size, void* d_ws, size_t ws_size,
                              hipStream_t stream) {
  const float* init_emb = (const float*)d_in[0];
  const int*   ei  = (const int*)d_in[1];
  const float* W1p = (const float*)d_in[2];
  const float* W1n = (const float*)d_in[3];
  const float* W1s = (const float*)d_in[4];
  const float* Wlp = (const float*)d_in[5];
  const float* Wln = (const float*)d_in[6];
  const float* Wls = (const float*)d_in[7];
  const float* lnw = (const float*)d_in[8];
  const float* lnb = (const float*)d_in[9];
  const float* gw  = (const float*)d_in[10];
  const float* gb  = (const float*)d_in[11];
  const float* pw  = (const float*)d_in[12];
  const float* pb  = (const float*)d_in[13];
  const float* w1  = (const float*)d_in[14];
  const float* b1  = (const float*)d_in[15];
  const float* l1w = (const float*)d_in[16];
  const float* l1b = (const float*)d_in[17];
  const float* w2  = (const float*)d_in[18];
  const float* b2  = (const float*)d_in[19];
  const float* l2w = (const float*)d_in[20];
  const float* l2b = (const float*)d_in[21];
  const float* w3  = (const float*)d_in[22];
  const float* b3  = (const float*)d_in[23];

  char* ws = (char*)d_ws;
  size_t off = 0;
  auto alloc = [&](size_t b) { void* p = ws + off; off = (off + b + 255) & ~(size_t)255; return p; };
  __hip_bfloat16* ypb = (__hip_bfloat16*)alloc(NODES * 32 * 2);
  __hip_bfloat16* ynb = (__hip_bfloat16*)alloc(NODES * 32 * 2);
  float*    ysel   = (float*)alloc(NODES * 32 * 4);
  float*    zA     = (float*)alloc(NODES * 32 * 4);
  float*    zB     = (float*)alloc(NODES * 32 * 4);
  unsigned* perm   = (unsigned*)alloc(EDGES * 4);
  int*      deg    = (int*)alloc(NODES * 4);
  int*      offs   = (int*)alloc((NODES + 1) * 4);
  int*      cursor = (int*)alloc(NODES * 4);
  int*      bsum   = (int*)alloc(128 * 4);

  // ---- CSR build ----
  hipMemsetAsync(deg, 0, NODES * 4, stream);
  k_hist<<<(EDGES + 255) / 256, 256, 0, stream>>>(ei, deg);
  int nb = (NODES + 511) / 512;
  k_scan1<<<nb, 512, 0, stream>>>(deg, offs, bsum);
  k_scan2<<<1, 128, 0, stream>>>(bsum, nb);
  k_scan3<<<nb, 512, 0, stream>>>(offs, bsum, cursor);
  k_scatter<<<(EDGES + 255) / 256, 256, 0, stream>>>(ei, cursor, perm);

  // ---- layer 1 (K=64) + ASFR(+lin Wl[0]) ----
  k_lin<64><<<NODES / 8, 256, 0, stream>>>(init_emb, W1p, W1n, W1s, ypb, ynb, ysel);
  k_agg<<<NODES / 8, 256, 0, stream>>>((const unsigned short*)ypb, (const unsigned short*)ynb,
                                       ysel, perm, offs, nullptr, zA);
  k_asfr_lin<<<NODES / 8, 256, 0, stream>>>(zA, lnw, lnb, gw, gb, Wlp, Wln, Wls, ypb, ynb, ysel);

  // ---- loop i=0..7: agg (residual for i>0), then lin with Wl[i+1] ----
  float* zo = zB;
  float* zr = nullptr;
  for (int i = 0; i < 8; i++) {
    k_agg<<<NODES / 8, 256, 0, stream>>>((const unsigned short*)ypb, (const unsigned short*)ynb,
                                         ysel, perm, offs, zr, zo);
    if (i < 7)
      k_lin<32><<<NODES / 8, 256, 0, stream>>>(zo, Wlp + (i + 1) * 1024, Wln + (i + 1) * 1024,
                                               Wls + (i + 1) * 1024, ypb, ynb, ysel);
    zr = zo;
    zo = (zo == zB) ? zA : zB;
  }

  // ---- fused head ----
  float* outz = (float*)d_out;
  float* outp = outz + (size_t)NODES * 64;
  k_mlp<<<(NODES * 4 + 255) / 256, 256, 0, stream>>>(zr, pw, pb, w1, b1, l1w, l1b,
                                                     w2, b2, l2w, l2b, w3, b3, outz, outp);
}

// Round 4
// 407.455 us; speedup vs baseline: 3.0605x; 1.1760x over previous
//
#include <hip/hip_runtime.h>
#include <hip/hip_bf16.h>

#define NODES 50000
#define EDGES 800000

__device__ __forceinline__ float elu1(float x) { return x > 0.f ? x : expm1f(x); }

union F4 { float4 v; float f[4]; };

// ---------------- CSR build ----------------
__global__ __launch_bounds__(256) void k_hist(const int* __restrict__ ei, int* __restrict__ deg) {
  int e = blockIdx.x * 256 + threadIdx.x;
  if (e < EDGES) atomicAdd(deg + ei[e * 3 + 1], 1);
}

__global__ __launch_bounds__(512) void k_scan1(const int* __restrict__ deg, int* __restrict__ offs,
                                               int* __restrict__ bsum) {
  __shared__ int s[512];
  int t = threadIdx.x, i = blockIdx.x * 512 + t;
  int v = (i < NODES) ? deg[i] : 0;
  s[t] = v;
  __syncthreads();
  for (int o = 1; o < 512; o <<= 1) {
    int x = (t >= o) ? s[t - o] : 0;
    __syncthreads();
    s[t] += x;
    __syncthreads();
  }
  if (i < NODES) offs[i] = s[t] - v;
  if (t == 511) bsum[blockIdx.x] = s[511];
}

__global__ __launch_bounds__(128) void k_scan2(int* __restrict__ bsum, int nb) {
  __shared__ int s[128];
  int t = threadIdx.x;
  int v = (t < nb) ? bsum[t] : 0;
  s[t] = v;
  __syncthreads();
  for (int o = 1; o < 128; o <<= 1) {
    int x = (t >= o) ? s[t - o] : 0;
    __syncthreads();
    s[t] += x;
    __syncthreads();
  }
  if (t < nb) bsum[t] = s[t] - v;
}

__global__ __launch_bounds__(512) void k_scan3(int* __restrict__ offs, const int* __restrict__ bsum,
                                               int* __restrict__ cursor) {
  int i = blockIdx.x * 512 + threadIdx.x;
  if (i < NODES) {
    int v = offs[i] + bsum[blockIdx.x];
    offs[i] = v;
    cursor[i] = v;
  }
  if (i == 0) offs[NODES] = EDGES;
}

__global__ __launch_bounds__(256) void k_scatter(const int* __restrict__ ei, int* __restrict__ cursor,
                                                 unsigned* __restrict__ perm) {
  int e = blockIdx.x * 256 + threadIdx.x;
  if (e >= EDGES) return;
  int src = ei[e * 3 + 0];
  int tgt = ei[e * 3 + 1];
  int sg  = ei[e * 3 + 2];
  int p = atomicAdd(cursor + tgt, 1);
  perm[p] = (unsigned)src | (sg < 0 ? 0x80000000u : 0u);
}

// ---------------- first linear: y = x @ {Wp,Wn,Ws}.T (out 32, K=64) ----------------
__global__ __launch_bounds__(256) void k_lin64(const float* __restrict__ x,
    const float* __restrict__ Wp, const float* __restrict__ Wn, const float* __restrict__ Ws,
    __hip_bfloat16* __restrict__ ypb, __hip_bfloat16* __restrict__ ynb, float* __restrict__ ys) {
  constexpr int K4 = 16;
  __shared__ float4 wp[K4][32], wn[K4][32], wsm[K4][32];  // [k4][out-col]
  __shared__ float4 xs[8][K4];
  for (int i = threadIdx.x; i < 32 * K4; i += 256) {
    int k4 = i >> 5, c = i & 31;
    wp[k4][c]  = ((const float4*)Wp)[c * K4 + k4];
    wn[k4][c]  = ((const float4*)Wn)[c * K4 + k4];
    wsm[k4][c] = ((const float4*)Ws)[c * K4 + k4];
  }
  int base = blockIdx.x * 8;
  for (int i = threadIdx.x; i < 8 * K4; i += 256) {
    int r = i / K4, k4 = i - r * K4;
    xs[r][k4] = ((const float4*)(x + (size_t)(base + r) * 64))[k4];
  }
  __syncthreads();
  int lane = threadIdx.x & 31, local = threadIdx.x >> 5;
  float ap = 0.f, an = 0.f, asf = 0.f;
#pragma unroll
  for (int k4 = 0; k4 < K4; k4++) {
    float4 xv = xs[local][k4];
    float4 a = wp[k4][lane], b = wn[k4][lane], c = wsm[k4][lane];
    ap  = fmaf(xv.w, a.w, fmaf(xv.z, a.z, fmaf(xv.y, a.y, fmaf(xv.x, a.x, ap))));
    an  = fmaf(xv.w, b.w, fmaf(xv.z, b.z, fmaf(xv.y, b.y, fmaf(xv.x, b.x, an))));
    asf = fmaf(xv.w, c.w, fmaf(xv.z, c.z, fmaf(xv.y, c.y, fmaf(xv.x, c.x, asf))));
  }
  size_t o = (size_t)(base + local) * 32 + lane;
  ypb[o] = __float2bfloat16(ap);
  ynb[o] = __float2bfloat16(an);
  ys[o] = asf;
}

// ---------------- fused layer: agg(+ELU)(+res)(+ASFR)(+lin next) ----------------
// ys and z are node-local (read-before-write by owning block) -> single buffers.
// yp/yn are gathered across blocks -> ping-pong in/out.
template <int DO_ASFR, int DO_RES, int DO_LIN, int WRITE_Z>
__global__ __launch_bounds__(256) void k_layer(
    const unsigned short* __restrict__ ypi, const unsigned short* __restrict__ yni,
    float* __restrict__ ys,
    const unsigned* __restrict__ perm, const int* __restrict__ offs,
    float* __restrict__ z,
    const float* __restrict__ lnw, const float* __restrict__ lnb,
    const float* __restrict__ gw, const float* __restrict__ gb,
    const float* __restrict__ Wp, const float* __restrict__ Wn, const float* __restrict__ Ws,
    __hip_bfloat16* __restrict__ ypo, __hip_bfloat16* __restrict__ yno) {
  __shared__ float4 wps[8][32], wns[8][32], wss[8][32], gws[8][32];
  __shared__ float zrow[8][36], xrow[8][36];
  int t = threadIdx.x;
  if (DO_LIN) {
    int k4 = t >> 5, c = t & 31;  // 256 threads = exactly 8*32
    wps[k4][c] = ((const float4*)Wp)[c * 8 + k4];
    wns[k4][c] = ((const float4*)Wn)[c * 8 + k4];
    wss[k4][c] = ((const float4*)Ws)[c * 8 + k4];
    if (DO_ASFR) gws[k4][c] = ((const float4*)gw)[c * 8 + k4];
  }
  int lane = t & 31, local = t >> 5;
  int node = blockIdx.x * 8 + local;
  int es = lane >> 2, fs = lane & 3;  // 8 edge slots x 4 lanes (16B each)
  int beg = offs[node], end = offs[node + 1];
  float a[8];
#pragma unroll
  for (int i = 0; i < 8; i++) a[i] = 0.f;
#pragma unroll 2
  for (int b = beg + es; b < end; b += 8) {
    unsigned u = perm[b];
    const unsigned short* base = (u >> 31) ? yni : ypi;
    uint4 v = *((const uint4*)(base + (size_t)(u & 0x7FFFFFFFu) * 32) + fs);
    a[0] += __uint_as_float(v.x << 16);
    a[1] += __uint_as_float(v.x & 0xffff0000u);
    a[2] += __uint_as_float(v.y << 16);
    a[3] += __uint_as_float(v.y & 0xffff0000u);
    a[4] += __uint_as_float(v.z << 16);
    a[5] += __uint_as_float(v.z & 0xffff0000u);
    a[6] += __uint_as_float(v.w << 16);
    a[7] += __uint_as_float(v.w & 0xffff0000u);
  }
#pragma unroll
  for (int m = 4; m <= 16; m <<= 1) {
#pragma unroll
    for (int i = 0; i < 8; i++) a[i] += __shfl_xor(a[i], m, 32);
  }
  if (es == 0) {  // 4 lanes per node finalize 8 floats each
    const float* ysr = ys + (size_t)node * 32 + fs * 8;
    F4 s0, s1;
    s0.v = *(const float4*)ysr;
    s1.v = *(const float4*)(ysr + 4);
    float o[8];
#pragma unroll
    for (int i = 0; i < 4; i++) o[i] = elu1(a[i] + s0.f[i]);
#pragma unroll
    for (int i = 0; i < 4; i++) o[4 + i] = elu1(a[4 + i] + s1.f[i]);
    if (DO_RES) {
      const float* rr = z + (size_t)node * 32 + fs * 8;
      F4 r0, r1;
      r0.v = *(const float4*)rr;
      r1.v = *(const float4*)(rr + 4);
#pragma unroll
      for (int i = 0; i < 4; i++) { o[i] += 0.1f * r0.f[i]; o[4 + i] += 0.1f * r1.f[i]; }
    }
#pragma unroll
    for (int i = 0; i < 8; i++) zrow[local][fs * 8 + i] = o[i];
    if (WRITE_Z) {
      float* zw = z + (size_t)node * 32 + fs * 8;
      *(float4*)zw = make_float4(o[0], o[1], o[2], o[3]);
      *(float4*)(zw + 4) = make_float4(o[4], o[5], o[6], o[7]);
    }
  }
  __syncthreads();  // weights staged (cross-wave) + zrow (in-wave) ready
  if (!DO_LIN) return;
  if (DO_ASFR) {
    float v = zrow[local][lane];
    float s = v;
#pragma unroll
    for (int m = 16; m; m >>= 1) s += __shfl_xor(s, m, 32);
    float mu = s * (1.f / 32.f);
    float d = v - mu, sq = d * d;
#pragma unroll
    for (int m = 16; m; m >>= 1) sq += __shfl_xor(sq, m, 32);
    float xn = d * rsqrtf(sq * (1.f / 32.f) + 1e-5f) * lnw[lane] + lnb[lane];
    xrow[local][lane] = xn;  // in-wave
    float ga = gb[lane];
#pragma unroll
    for (int k4 = 0; k4 < 8; k4++) {
      float4 xv = *((const float4*)&xrow[local][0] + k4);
      float4 w = gws[k4][lane];
      ga = fmaf(xv.w, w.w, fmaf(xv.z, w.z, fmaf(xv.y, w.y, fmaf(xv.x, w.x, ga))));
    }
    float g = 1.f / (1.f + __expf(-ga));
    float w1 = g > 0.5f ? 1.f : g;
    float w2 = g > 0.5f ? 0.f : g;
    float zn = w1 * v + __shfl_xor(w2 * v, 16, 32);
    zrow[local][lane] = zn;  // in-wave
  }
  float ap = 0.f, an = 0.f, asf = 0.f;
#pragma unroll
  for (int k4 = 0; k4 < 8; k4++) {
    float4 xv = *((const float4*)&zrow[local][0] + k4);
    float4 a2 = wps[k4][lane], b2 = wns[k4][lane], c2 = wss[k4][lane];
    ap  = fmaf(xv.w, a2.w, fmaf(xv.z, a2.z, fmaf(xv.y, a2.y, fmaf(xv.x, a2.x, ap))));
    an  = fmaf(xv.w, b2.w, fmaf(xv.z, b2.z, fmaf(xv.y, b2.y, fmaf(xv.x, b2.x, an))));
    asf = fmaf(xv.w, c2.w, fmaf(xv.z, c2.z, fmaf(xv.y, c2.y, fmaf(xv.x, c2.x, asf))));
  }
  size_t o = (size_t)node * 32 + lane;
  ypo[o] = __float2bfloat16(ap);
  yno[o] = __float2bfloat16(an);
  ys[o] = asf;  // node-local overwrite, safe (read happened above in this block)
}

// ---------------- head: 4 lanes/node, rolled K-loops, LDS h-exchange ----------------
__global__ __launch_bounds__(256) void k_mlp(const float* __restrict__ z,
    const float* __restrict__ pw, const float* __restrict__ pb,
    const float* __restrict__ w1, const float* __restrict__ b1,
    const float* __restrict__ l1w, const float* __restrict__ l1b,
    const float* __restrict__ w2, const float* __restrict__ b2,
    const float* __restrict__ l2w, const float* __restrict__ l2b,
    const float* __restrict__ w3, const float* __restrict__ b3,
    float* __restrict__ outz, float* __restrict__ outp) {
  __shared__ float4 pT4[32 * 16];
  __shared__ float4 w1T4[64 * 16], w2T4[64 * 16];
  __shared__ float4 hbuf4[64 * 17];
  __shared__ float pb_s[64], b1_s[64], l1w_s[64], l1b_s[64], b2_s[64], l2w_s[64], l2b_s[64], w3_s[64];
  int t = threadIdx.x;
  for (int i = t; i < 512; i += 256) {
    int k = i >> 4, j4 = i & 15;
    float4 v;
    v.x = pw[(j4 * 4 + 0) * 32 + k]; v.y = pw[(j4 * 4 + 1) * 32 + k];
    v.z = pw[(j4 * 4 + 2) * 32 + k]; v.w = pw[(j4 * 4 + 3) * 32 + k];
    pT4[i] = v;
  }
  for (int i = t; i < 1024; i += 256) {
    int k = i >> 4, j4 = i & 15;
    float4 v, u;
    v.x = w1[(j4 * 4 + 0) * 64 + k]; v.y = w1[(j4 * 4 + 1) * 64 + k];
    v.z = w1[(j4 * 4 + 2) * 64 + k]; v.w = w1[(j4 * 4 + 3) * 64 + k];
    u.x = w2[(j4 * 4 + 0) * 64 + k]; u.y = w2[(j4 * 4 + 1) * 64 + k];
    u.z = w2[(j4 * 4 + 2) * 64 + k]; u.w = w2[(j4 * 4 + 3) * 64 + k];
    w1T4[i] = v; w2T4[i] = u;
  }
  if (t < 64) {
    pb_s[t] = pb[t]; b1_s[t] = b1[t]; l1w_s[t] = l1w[t]; l1b_s[t] = l1b[t];
    b2_s[t] = b2[t]; l2w_s[t] = l2w[t]; l2b_s[t] = l2b[t]; w3_s[t] = w3[t];
  }
  __syncthreads();
  int g = t >> 2, q = t & 3;
  int node = blockIdx.x * 64 + g;
  if (node >= NODES) return;
  float bb3 = b3[0];
  {
    const float4* z4 = (const float4*)(z + (size_t)node * 32);
    hbuf4[g * 17 + q * 2 + 0] = z4[q * 2 + 0];
    hbuf4[g * 17 + q * 2 + 1] = z4[q * 2 + 1];
  }
  float acc[16], h[16];
#pragma unroll
  for (int i = 0; i < 16; i++) acc[i] = pb_s[q * 16 + i];
#pragma unroll 2
  for (int k4 = 0; k4 < 8; k4++) {
    F4 hv; hv.v = hbuf4[g * 17 + k4];
#pragma unroll
    for (int c = 0; c < 4; c++) {
      float hk = hv.f[c];
      const float4* wrow = &pT4[(k4 * 4 + c) * 16 + q * 4];
#pragma unroll
      for (int j4 = 0; j4 < 4; j4++) {
        float4 w = wrow[j4];
        acc[j4 * 4 + 0] = fmaf(hk, w.x, acc[j4 * 4 + 0]);
        acc[j4 * 4 + 1] = fmaf(hk, w.y, acc[j4 * 4 + 1]);
        acc[j4 * 4 + 2] = fmaf(hk, w.z, acc[j4 * 4 + 2]);
        acc[j4 * 4 + 3] = fmaf(hk, w.w, acc[j4 * 4 + 3]);
      }
    }
  }
#pragma unroll
  for (int i = 0; i < 16; i++) h[i] = elu1(acc[i]);
  {
    float4* oz = (float4*)(outz + (size_t)node * 64 + q * 16);
#pragma unroll
    for (int i4 = 0; i4 < 4; i4++)
      oz[i4] = make_float4(h[i4 * 4], h[i4 * 4 + 1], h[i4 * 4 + 2], h[i4 * 4 + 3]);
#pragma unroll
    for (int i4 = 0; i4 < 4; i4++)
      hbuf4[g * 17 + q * 4 + i4] = make_float4(h[i4 * 4], h[i4 * 4 + 1], h[i4 * 4 + 2], h[i4 * 4 + 3]);
  }
#pragma unroll
  for (int i = 0; i < 16; i++) acc[i] = b1_s[q * 16 + i];
#pragma unroll 2
  for (int k4 = 0; k4 < 16; k4++) {
    F4 hv; hv.v = hbuf4[g * 17 + k4];
#pragma unroll
    for (int c = 0; c < 4; c++) {
      float hk = hv.f[c];
      const float4* wrow = &w1T4[(k4 * 4 + c) * 16 + q * 4];
#pragma unroll
      for (int j4 = 0; j4 < 4; j4++) {
        float4 w = wrow[j4];
        acc[j4 * 4 + 0] = fmaf(hk, w.x, acc[j4 * 4 + 0]);
        acc[j4 * 4 + 1] = fmaf(hk, w.y, acc[j4 * 4 + 1]);
        acc[j4 * 4 + 2] = fmaf(hk, w.z, acc[j4 * 4 + 2]);
        acc[j4 * 4 + 3] = fmaf(hk, w.w, acc[j4 * 4 + 3]);
      }
    }
  }
  {
    float s = 0.f;
#pragma unroll
    for (int i = 0; i < 16; i++) s += acc[i];
    s += __shfl_xor(s, 1, 4); s += __shfl_xor(s, 2, 4);
    float mu = s * (1.f / 64.f);
    float vs = 0.f;
#pragma unroll
    for (int i = 0; i < 16; i++) { float dd = acc[i] - mu; vs += dd * dd; }
    vs += __shfl_xor(vs, 1, 4); vs += __shfl_xor(vs, 2, 4);
    float rs = rsqrtf(vs * (1.f / 64.f) + 1e-5f);
#pragma unroll
    for (int i = 0; i < 16; i++)
      h[i] = fmaxf((acc[i] - mu) * rs * l1w_s[q * 16 + i] + l1b_s[q * 16 + i], 0.f);
  }
#pragma unroll
  for (int i4 = 0; i4 < 4; i4++)
    hbuf4[g * 17 + q * 4 + i4] = make_float4(h[i4 * 4], h[i4 * 4 + 1], h[i4 * 4 + 2], h[i4 * 4 + 3]);
#pragma unroll
  for (int i = 0; i < 16; i++) acc[i] = b2_s[q * 16 + i];
#pragma unroll 2
  for (int k4 = 0; k4 < 16; k4++) {
    F4 hv; hv.v = hbuf4[g * 17 + k4];
#pragma unroll
    for (int c = 0; c < 4; c++) {
      float hk = hv.f[c];
      const float4* wrow = &w2T4[(k4 * 4 + c) * 16 + q * 4];
#pragma unroll
      for (int j4 = 0; j4 < 4; j4++) {
        float4 w = wrow[j4];
        acc[j4 * 4 + 0] = fmaf(hk, w.x, acc[j4 * 4 + 0]);
        acc[j4 * 4 + 1] = fmaf(hk, w.y, acc[j4 * 4 + 1]);
        acc[j4 * 4 + 2] = fmaf(hk, w.z, acc[j4 * 4 + 2]);
        acc[j4 * 4 + 3] = fmaf(hk, w.w, acc[j4 * 4 + 3]);
      }
    }
  }
  {
    float s = 0.f;
#pragma unroll
    for (int i = 0; i < 16; i++) s += acc[i];
    s += __shfl_xor(s, 1, 4); s += __shfl_xor(s, 2, 4);
    float mu = s * (1.f / 64.f);
    float vs = 0.f;
#pragma unroll
    for (int i = 0; i < 16; i++) { float dd = acc[i] - mu; vs += dd * dd; }
    vs += __shfl_xor(vs, 1, 4); vs += __shfl_xor(vs, 2, 4);
    float rs = rsqrtf(vs * (1.f / 64.f) + 1e-5f);
    float p = 0.f;
#pragma unroll
    for (int i = 0; i < 16; i++) {
      float hv2 = fmaxf((acc[i] - mu) * rs * l2w_s[q * 16 + i] + l2b_s[q * 16 + i], 0.f);
      p = fmaf(hv2, w3_s[q * 16 + i], p);
    }
    p += __shfl_xor(p, 1, 4); p += __shfl_xor(p, 2, 4);
    if (q == 0) outp[node] = 1.f / (1.f + __expf(-(p + bb3)));
  }
}

extern "C" void kernel_launch(void* const* d_in, const int* in_sizes, int n_in,
                              void* d_out, int out_size, void* d_ws, size_t ws_size,
                              hipStream_t stream) {
  const float* init_emb = (const float*)d_in[0];
  const int*   ei  = (const int*)d_in[1];
  const float* W1p = (const float*)d_in[2];
  const float* W1n = (const float*)d_in[3];
  const float* W1s = (const float*)d_in[4];
  const float* Wlp = (const float*)d_in[5];
  const float* Wln = (const float*)d_in[6];
  const float* Wls = (const float*)d_in[7];
  const float* lnw = (const float*)d_in[8];
  const float* lnb = (const float*)d_in[9];
  const float* gw  = (const float*)d_in[10];
  const float* gb  = (const float*)d_in[11];
  const float* pw  = (const float*)d_in[12];
  const float* pb  = (const float*)d_in[13];
  const float* w1  = (const float*)d_in[14];
  const float* b1  = (const float*)d_in[15];
  const float* l1w = (const float*)d_in[16];
  const float* l1b = (const float*)d_in[17];
  const float* w2  = (const float*)d_in[18];
  const float* b2  = (const float*)d_in[19];
  const float* l2w = (const float*)d_in[20];
  const float* l2b = (const float*)d_in[21];
  const float* w3  = (const float*)d_in[22];
  const float* b3  = (const float*)d_in[23];

  char* ws = (char*)d_ws;
  size_t off = 0;
  auto alloc = [&](size_t b) { void* p = ws + off; off = (off + b + 255) & ~(size_t)255; return p; };
  __hip_bfloat16* ypA = (__hip_bfloat16*)alloc(NODES * 32 * 2);
  __hip_bfloat16* ynA = (__hip_bfloat16*)alloc(NODES * 32 * 2);
  __hip_bfloat16* ypB = (__hip_bfloat16*)alloc(NODES * 32 * 2);
  __hip_bfloat16* ynB = (__hip_bfloat16*)alloc(NODES * 32 * 2);
  float*    ysel   = (float*)alloc(NODES * 32 * 4);
  float*    zbuf   = (float*)alloc(NODES * 32 * 4);
  unsigned* perm   = (unsigned*)alloc(EDGES * 4);
  int*      deg    = (int*)alloc(NODES * 4);
  int*      offs   = (int*)alloc((NODES + 1) * 4);
  int*      cursor = (int*)alloc(NODES * 4);
  int*      bsum   = (int*)alloc(128 * 4);

  // ---- CSR build ----
  hipMemsetAsync(deg, 0, NODES * 4, stream);
  k_hist<<<(EDGES + 255) / 256, 256, 0, stream>>>(ei, deg);
  int nb = (NODES + 511) / 512;
  k_scan1<<<nb, 512, 0, stream>>>(deg, offs, bsum);
  k_scan2<<<1, 128, 0, stream>>>(bsum, nb);
  k_scan3<<<nb, 512, 0, stream>>>(offs, bsum, cursor);
  k_scatter<<<(EDGES + 255) / 256, 256, 0, stream>>>(ei, cursor, perm);

  const int G = NODES / 8;
  // layer 1 conv (K=64) -> yA
  k_lin64<<<G, 256, 0, stream>>>(init_emb, W1p, W1n, W1s, ypA, ynA, ysel);
  // L0: agg + ASFR + lin(Wl[0]); no residual, no z write; yA -> yB
  k_layer<1, 0, 1, 0><<<G, 256, 0, stream>>>((const unsigned short*)ypA, (const unsigned short*)ynA,
      ysel, perm, offs, zbuf, lnw, lnb, gw, gb, Wlp, Wln, Wls, ypB, ynB);
  // L1 (loop i=0): agg no residual, write z, lin Wl[1]; yB -> yA
  k_layer<0, 0, 1, 1><<<G, 256, 0, stream>>>((const unsigned short*)ypB, (const unsigned short*)ynB,
      ysel, perm, offs, zbuf, nullptr, nullptr, nullptr, nullptr,
      Wlp + 1024, Wln + 1024, Wls + 1024, ypA, ynA);
  // L2..L7 (loop i=1..6): agg + residual, write z, lin Wl[2..7]; alternate buffers
  const __hip_bfloat16* yin_p = ypA; const __hip_bfloat16* yin_n = ynA;
  __hip_bfloat16* yout_p = ypB; __hip_bfloat16* yout_n = ynB;
  for (int i = 1; i < 7; i++) {
    k_layer<0, 1, 1, 1><<<G, 256, 0, stream>>>((const unsigned short*)yin_p, (const unsigned short*)yin_n,
        ysel, perm, offs, zbuf, nullptr, nullptr, nullptr, nullptr,
        Wlp + (i + 1) * 1024, Wln + (i + 1) * 1024, Wls + (i + 1) * 1024, yout_p, yout_n);
    const __hip_bfloat16* tp = yin_p; const __hip_bfloat16* tn = yin_n;
    yin_p = yout_p; yin_n = yout_n;
    yout_p = (__hip_bfloat16*)tp; yout_n = (__hip_bfloat16*)tn;
  }
  // L8 (loop i=7): agg + residual, write z, no lin
  k_layer<0, 1, 0, 1><<<G, 256, 0, stream>>>((const unsigned short*)yin_p, (const unsigned short*)yin_n,
      ysel, perm, offs, zbuf, nullptr, nullptr, nullptr, nullptr,
      nullptr, nullptr, nullptr, nullptr, nullptr);

  // ---- fused head ----
  float* outz = (float*)d_out;
  float* outp = outz + (size_t)NODES * 64;
  k_mlp<<<(NODES * 4 + 255) / 256, 256, 0, stream>>>(zbuf, pw, pb, w1, b1, l1w, l1b,
                                                     w2, b2, l2w, l2b, w3, b3, outz, outp);
}

// Round 5
// 395.665 us; speedup vs baseline: 3.1517x; 1.0298x over previous
//
#include <hip/hip_runtime.h>
#include <hip/hip_bf16.h>

#define NODES 50000
#define EDGES 800000
#define BSH 8
#define NBUCK 196          // ceil(50000 / 256)
#define NBIN_BLOCKS 391    // ceil(800000 / 2048)

__device__ __forceinline__ float elu1(float x) { return x > 0.f ? x : expm1f(x); }

union F4 { float4 v; float f[4]; };

// ---------------- CSR build: hist + bucket counts ----------------
__global__ __launch_bounds__(256) void k_hist2(const int* __restrict__ ei, int* __restrict__ deg,
                                               int* __restrict__ bucket_cnt) {
  __shared__ int cnt[NBUCK];
  int t = threadIdx.x;
  for (int i = t; i < NBUCK; i += 256) cnt[i] = 0;
  __syncthreads();
  int base = blockIdx.x * 2048;
#pragma unroll
  for (int i = 0; i < 8; i++) {
    int e = base + i * 256 + t;
    if (e < EDGES) {
      int tgt = ei[e * 3 + 1];
      atomicAdd(deg + tgt, 1);
      atomicAdd(&cnt[tgt >> BSH], 1);
    }
  }
  __syncthreads();
  for (int i = t; i < NBUCK; i += 256)
    if (cnt[i]) atomicAdd(bucket_cnt + i, cnt[i]);
}

__global__ __launch_bounds__(512) void k_scan1(const int* __restrict__ deg, int* __restrict__ offs,
                                               int* __restrict__ bsum) {
  __shared__ int s[512];
  int t = threadIdx.x, i = blockIdx.x * 512 + t;
  int v = (i < NODES) ? deg[i] : 0;
  s[t] = v;
  __syncthreads();
  for (int o = 1; o < 512; o <<= 1) {
    int x = (t >= o) ? s[t - o] : 0;
    __syncthreads();
    s[t] += x;
    __syncthreads();
  }
  if (i < NODES) offs[i] = s[t] - v;
  if (t == 511) bsum[blockIdx.x] = s[511];
}

__global__ __launch_bounds__(128) void k_scan2(int* __restrict__ bsum, int nb) {
  __shared__ int s[128];
  int t = threadIdx.x;
  int v = (t < nb) ? bsum[t] : 0;
  s[t] = v;
  __syncthreads();
  for (int o = 1; o < 128; o <<= 1) {
    int x = (t >= o) ? s[t - o] : 0;
    __syncthreads();
    s[t] += x;
    __syncthreads();
  }
  if (t < nb) bsum[t] = s[t] - v;
}

__global__ __launch_bounds__(512) void k_scan3(int* __restrict__ offs, const int* __restrict__ bsum) {
  int i = blockIdx.x * 512 + threadIdx.x;
  if (i < NODES) offs[i] += bsum[blockIdx.x];
  if (i == 0) offs[NODES] = EDGES;
}

// exclusive scan over 196 bucket counts -> bucket_base (pass B ranges) + bucket_cursor (pass A alloc)
__global__ __launch_bounds__(256) void k_bscan(const int* __restrict__ bucket_cnt,
                                               int* __restrict__ bucket_base,
                                               int* __restrict__ bucket_cursor) {
  __shared__ int s[256];
  int t = threadIdx.x;
  int v = (t < NBUCK) ? bucket_cnt[t] : 0;
  s[t] = v;
  __syncthreads();
  for (int o = 1; o < 256; o <<= 1) {
    int x = (t >= o) ? s[t - o] : 0;
    __syncthreads();
    s[t] += x;
    __syncthreads();
  }
  if (t < NBUCK) { int e = s[t] - v; bucket_base[t] = e; bucket_cursor[t] = e; }
}

// pass A: bin edges by tgt-bucket into binned[] as (val, tgt) pairs
__global__ __launch_bounds__(256) void k_bin(const int* __restrict__ ei,
                                             int* __restrict__ bucket_cursor,
                                             uint2* __restrict__ binned) {
  __shared__ int cnt[NBUCK], base[NBUCK];
  int t = threadIdx.x;
  for (int i = t; i < NBUCK; i += 256) cnt[i] = 0;
  __syncthreads();
  int eb = blockIdx.x * 2048;
#pragma unroll
  for (int i = 0; i < 8; i++) {
    int e = eb + i * 256 + t;
    if (e < EDGES) atomicAdd(&cnt[ei[e * 3 + 1] >> BSH], 1);
  }
  __syncthreads();
  for (int i = t; i < NBUCK; i += 256) {
    int c = cnt[i];
    base[i] = c ? atomicAdd(bucket_cursor + i, c) : 0;
    cnt[i] = 0;
  }
  __syncthreads();
#pragma unroll
  for (int i = 0; i < 8; i++) {
    int e = eb + i * 256 + t;
    if (e < EDGES) {
      int src = ei[e * 3 + 0];
      int tgt = ei[e * 3 + 1];
      int sg  = ei[e * 3 + 2];
      unsigned val = (unsigned)src | (sg < 0 ? 0x80000000u : 0u);
      int bkt = tgt >> BSH;
      int r = atomicAdd(&cnt[bkt], 1);
      binned[base[bkt] + r] = make_uint2(val, (unsigned)tgt);
    }
  }
}

// pass B: one block per bucket; per-tgt cursors in LDS; writes confined to one 16KB region
__global__ __launch_bounds__(256) void k_scatter2(const uint2* __restrict__ binned,
                                                  const int* __restrict__ bucket_base,
                                                  const int* __restrict__ bucket_cnt,
                                                  const int* __restrict__ offs,
                                                  unsigned* __restrict__ perm) {
  __shared__ int cur[256];
  int b = blockIdx.x, t = threadIdx.x;
  int t0 = b << BSH;
  cur[t] = (t0 + t < NODES) ? offs[t0 + t] : 0;
  __syncthreads();
  int n = bucket_cnt[b], bb = bucket_base[b];
  for (int i = t; i < n; i += 256) {
    uint2 e = binned[bb + i];
    int p = atomicAdd(&cur[e.y - t0], 1);
    perm[p] = e.x;
  }
}

// ---------------- first linear: y = x @ {Wp,Wn,Ws}.T (out 32, K=64) ----------------
__global__ __launch_bounds__(256) void k_lin64(const float* __restrict__ x,
    const float* __restrict__ Wp, const float* __restrict__ Wn, const float* __restrict__ Ws,
    __hip_bfloat16* __restrict__ ypb, __hip_bfloat16* __restrict__ ynb, float* __restrict__ ys) {
  constexpr int K4 = 16;
  __shared__ float4 wp[K4][32], wn[K4][32], wsm[K4][32];
  __shared__ float4 xs[8][K4];
  for (int i = threadIdx.x; i < 32 * K4; i += 256) {
    int k4 = i >> 5, c = i & 31;
    wp[k4][c]  = ((const float4*)Wp)[c * K4 + k4];
    wn[k4][c]  = ((const float4*)Wn)[c * K4 + k4];
    wsm[k4][c] = ((const float4*)Ws)[c * K4 + k4];
  }
  int base = blockIdx.x * 8;
  for (int i = threadIdx.x; i < 8 * K4; i += 256) {
    int r = i / K4, k4 = i - r * K4;
    xs[r][k4] = ((const float4*)(x + (size_t)(base + r) * 64))[k4];
  }
  __syncthreads();
  int lane = threadIdx.x & 31, local = threadIdx.x >> 5;
  float ap = 0.f, an = 0.f, asf = 0.f;
#pragma unroll
  for (int k4 = 0; k4 < K4; k4++) {
    float4 xv = xs[local][k4];
    float4 a = wp[k4][lane], b = wn[k4][lane], c = wsm[k4][lane];
    ap  = fmaf(xv.w, a.w, fmaf(xv.z, a.z, fmaf(xv.y, a.y, fmaf(xv.x, a.x, ap))));
    an  = fmaf(xv.w, b.w, fmaf(xv.z, b.z, fmaf(xv.y, b.y, fmaf(xv.x, b.x, an))));
    asf = fmaf(xv.w, c.w, fmaf(xv.z, c.z, fmaf(xv.y, c.y, fmaf(xv.x, c.x, asf))));
  }
  size_t o = (size_t)(base + local) * 32 + lane;
  ypb[o] = __float2bfloat16(ap);
  ynb[o] = __float2bfloat16(an);
  ys[o] = asf;
}

#define ACC8(A, V)                                   \
  A[0] += __uint_as_float((V).x << 16);              \
  A[1] += __uint_as_float((V).x & 0xffff0000u);      \
  A[2] += __uint_as_float((V).y << 16);              \
  A[3] += __uint_as_float((V).y & 0xffff0000u);      \
  A[4] += __uint_as_float((V).z << 16);              \
  A[5] += __uint_as_float((V).z & 0xffff0000u);      \
  A[6] += __uint_as_float((V).w << 16);              \
  A[7] += __uint_as_float((V).w & 0xffff0000u);

// ---------------- fused layer: agg(+ELU)(+res)(+ASFR)(+lin next) ----------------
template <int DO_ASFR, int DO_RES, int DO_LIN, int WRITE_Z>
__global__ __launch_bounds__(256) void k_layer(
    const unsigned short* __restrict__ ypi, const unsigned short* __restrict__ yni,
    float* __restrict__ ys,
    const unsigned* __restrict__ perm, const int* __restrict__ offs,
    float* __restrict__ z,
    const float* __restrict__ lnw, const float* __restrict__ lnb,
    const float* __restrict__ gw, const float* __restrict__ gb,
    const float* __restrict__ Wp, const float* __restrict__ Wn, const float* __restrict__ Ws,
    __hip_bfloat16* __restrict__ ypo, __hip_bfloat16* __restrict__ yno) {
  __shared__ float4 wps[8][32], wns[8][32], wss[8][32], gws[8][32];
  __shared__ float zrow[8][36], xrow[8][36];
  int t = threadIdx.x;
  if (DO_LIN) {
    int k4 = t >> 5, c = t & 31;
    wps[k4][c] = ((const float4*)Wp)[c * 8 + k4];
    wns[k4][c] = ((const float4*)Wn)[c * 8 + k4];
    wss[k4][c] = ((const float4*)Ws)[c * 8 + k4];
    if (DO_ASFR) gws[k4][c] = ((const float4*)gw)[c * 8 + k4];
  }
  int lane = t & 31, local = t >> 5;
  int node = blockIdx.x * 8 + local;
  int es = lane >> 2, fs = lane & 3;  // 8 edge slots x 4 lanes (16B each)
  int beg = offs[node], end = offs[node + 1];
  float a0[8], a1[8];
#pragma unroll
  for (int i = 0; i < 8; i++) { a0[i] = 0.f; a1[i] = 0.f; }
  int b = beg + es;
  for (; b + 8 < end; b += 16) {  // 16 edges in flight per node group
    unsigned u0 = perm[b];
    unsigned u1 = perm[b + 8];
    const unsigned short* p0 = (u0 >> 31) ? yni : ypi;
    const unsigned short* p1 = (u1 >> 31) ? yni : ypi;
    uint4 v0 = *((const uint4*)(p0 + (size_t)(u0 & 0x7FFFFFFFu) * 32) + fs);
    uint4 v1 = *((const uint4*)(p1 + (size_t)(u1 & 0x7FFFFFFFu) * 32) + fs);
    ACC8(a0, v0);
    ACC8(a1, v1);
  }
  if (b < end) {
    unsigned u0 = perm[b];
    const unsigned short* p0 = (u0 >> 31) ? yni : ypi;
    uint4 v0 = *((const uint4*)(p0 + (size_t)(u0 & 0x7FFFFFFFu) * 32) + fs);
    ACC8(a0, v0);
  }
#pragma unroll
  for (int i = 0; i < 8; i++) a0[i] += a1[i];
#pragma unroll
  for (int m = 4; m <= 16; m <<= 1) {
#pragma unroll
    for (int i = 0; i < 8; i++) a0[i] += __shfl_xor(a0[i], m, 32);
  }
  if (es == 0) {
    const float* ysr = ys + (size_t)node * 32 + fs * 8;
    F4 s0, s1;
    s0.v = *(const float4*)ysr;
    s1.v = *(const float4*)(ysr + 4);
    float o[8];
#pragma unroll
    for (int i = 0; i < 4; i++) o[i] = elu1(a0[i] + s0.f[i]);
#pragma unroll
    for (int i = 0; i < 4; i++) o[4 + i] = elu1(a0[4 + i] + s1.f[i]);
    if (DO_RES) {
      const float* rr = z + (size_t)node * 32 + fs * 8;
      F4 r0, r1;
      r0.v = *(const float4*)rr;
      r1.v = *(const float4*)(rr + 4);
#pragma unroll
      for (int i = 0; i < 4; i++) { o[i] += 0.1f * r0.f[i]; o[4 + i] += 0.1f * r1.f[i]; }
    }
#pragma unroll
    for (int i = 0; i < 8; i++) zrow[local][fs * 8 + i] = o[i];
    if (WRITE_Z) {
      float* zw = z + (size_t)node * 32 + fs * 8;
      *(float4*)zw = make_float4(o[0], o[1], o[2], o[3]);
      *(float4*)(zw + 4) = make_float4(o[4], o[5], o[6], o[7]);
    }
  }
  __syncthreads();
  if (!DO_LIN) return;
  if (DO_ASFR) {
    float v = zrow[local][lane];
    float s = v;
#pragma unroll
    for (int m = 16; m; m >>= 1) s += __shfl_xor(s, m, 32);
    float mu = s * (1.f / 32.f);
    float d = v - mu, sq = d * d;
#pragma unroll
    for (int m = 16; m; m >>= 1) sq += __shfl_xor(sq, m, 32);
    float xn = d * rsqrtf(sq * (1.f / 32.f) + 1e-5f) * lnw[lane] + lnb[lane];
    xrow[local][lane] = xn;
    float ga = gb[lane];
#pragma unroll
    for (int k4 = 0; k4 < 8; k4++) {
      float4 xv = *((const float4*)&xrow[local][0] + k4);
      float4 w = gws[k4][lane];
      ga = fmaf(xv.w, w.w, fmaf(xv.z, w.z, fmaf(xv.y, w.y, fmaf(xv.x, w.x, ga))));
    }
    float g = 1.f / (1.f + __expf(-ga));
    float w1 = g > 0.5f ? 1.f : g;
    float w2 = g > 0.5f ? 0.f : g;
    float zn = w1 * v + __shfl_xor(w2 * v, 16, 32);
    zrow[local][lane] = zn;
  }
  float ap = 0.f, an = 0.f, asf = 0.f;
#pragma unroll
  for (int k4 = 0; k4 < 8; k4++) {
    float4 xv = *((const float4*)&zrow[local][0] + k4);
    float4 a2 = wps[k4][lane], b2 = wns[k4][lane], c2 = wss[k4][lane];
    ap  = fmaf(xv.w, a2.w, fmaf(xv.z, a2.z, fmaf(xv.y, a2.y, fmaf(xv.x, a2.x, ap))));
    an  = fmaf(xv.w, b2.w, fmaf(xv.z, b2.z, fmaf(xv.y, b2.y, fmaf(xv.x, b2.x, an))));
    asf = fmaf(xv.w, c2.w, fmaf(xv.z, c2.z, fmaf(xv.y, c2.y, fmaf(xv.x, c2.x, asf))));
  }
  size_t o = (size_t)node * 32 + lane;
  ypo[o] = __float2bfloat16(ap);
  yno[o] = __float2bfloat16(an);
  ys[o] = asf;
}

// ---------------- head: 4 lanes/node, rolled K-loops, LDS h-exchange ----------------
__global__ __launch_bounds__(256) void k_mlp(const float* __restrict__ z,
    const float* __restrict__ pw, const float* __restrict__ pb,
    const float* __restrict__ w1, const float* __restrict__ b1,
    const float* __restrict__ l1w, const float* __restrict__ l1b,
    const float* __restrict__ w2, const float* __restrict__ b2,
    const float* __restrict__ l2w, const float* __restrict__ l2b,
    const float* __restrict__ w3, const float* __restrict__ b3,
    float* __restrict__ outz, float* __restrict__ outp) {
  __shared__ float4 pT4[32 * 16];
  __shared__ float4 w1T4[64 * 16], w2T4[64 * 16];
  __shared__ float4 hbuf4[64 * 17];
  __shared__ float pb_s[64], b1_s[64], l1w_s[64], l1b_s[64], b2_s[64], l2w_s[64], l2b_s[64], w3_s[64];
  int t = threadIdx.x;
  for (int i = t; i < 512; i += 256) {
    int k = i >> 4, j4 = i & 15;
    float4 v;
    v.x = pw[(j4 * 4 + 0) * 32 + k]; v.y = pw[(j4 * 4 + 1) * 32 + k];
    v.z = pw[(j4 * 4 + 2) * 32 + k]; v.w = pw[(j4 * 4 + 3) * 32 + k];
    pT4[i] = v;
  }
  for (int i = t; i < 1024; i += 256) {
    int k = i >> 4, j4 = i & 15;
    float4 v, u;
    v.x = w1[(j4 * 4 + 0) * 64 + k]; v.y = w1[(j4 * 4 + 1) * 64 + k];
    v.z = w1[(j4 * 4 + 2) * 64 + k]; v.w = w1[(j4 * 4 + 3) * 64 + k];
    u.x = w2[(j4 * 4 + 0) * 64 + k]; u.y = w2[(j4 * 4 + 1) * 64 + k];
    u.z = w2[(j4 * 4 + 2) * 64 + k]; u.w = w2[(j4 * 4 + 3) * 64 + k];
    w1T4[i] = v; w2T4[i] = u;
  }
  if (t < 64) {
    pb_s[t] = pb[t]; b1_s[t] = b1[t]; l1w_s[t] = l1w[t]; l1b_s[t] = l1b[t];
    b2_s[t] = b2[t]; l2w_s[t] = l2w[t]; l2b_s[t] = l2b[t]; w3_s[t] = w3[t];
  }
  __syncthreads();
  int g = t >> 2, q = t & 3;
  int node = blockIdx.x * 64 + g;
  if (node >= NODES) return;
  float bb3 = b3[0];
  {
    const float4* z4 = (const float4*)(z + (size_t)node * 32);
    hbuf4[g * 17 + q * 2 + 0] = z4[q * 2 + 0];
    hbuf4[g * 17 + q * 2 + 1] = z4[q * 2 + 1];
  }
  float acc[16], h[16];
#pragma unroll
  for (int i = 0; i < 16; i++) acc[i] = pb_s[q * 16 + i];
#pragma unroll 2
  for (int k4 = 0; k4 < 8; k4++) {
    F4 hv; hv.v = hbuf4[g * 17 + k4];
#pragma unroll
    for (int c = 0; c < 4; c++) {
      float hk = hv.f[c];
      const float4* wrow = &pT4[(k4 * 4 + c) * 16 + q * 4];
#pragma unroll
      for (int j4 = 0; j4 < 4; j4++) {
        float4 w = wrow[j4];
        acc[j4 * 4 + 0] = fmaf(hk, w.x, acc[j4 * 4 + 0]);
        acc[j4 * 4 + 1] = fmaf(hk, w.y, acc[j4 * 4 + 1]);
        acc[j4 * 4 + 2] = fmaf(hk, w.z, acc[j4 * 4 + 2]);
        acc[j4 * 4 + 3] = fmaf(hk, w.w, acc[j4 * 4 + 3]);
      }
    }
  }
#pragma unroll
  for (int i = 0; i < 16; i++) h[i] = elu1(acc[i]);
  {
    float4* oz = (float4*)(outz + (size_t)node * 64 + q * 16);
#pragma unroll
    for (int i4 = 0; i4 < 4; i4++)
      oz[i4] = make_float4(h[i4 * 4], h[i4 * 4 + 1], h[i4 * 4 + 2], h[i4 * 4 + 3]);
#pragma unroll
    for (int i4 = 0; i4 < 4; i4++)
      hbuf4[g * 17 + q * 4 + i4] = make_float4(h[i4 * 4], h[i4 * 4 + 1], h[i4 * 4 + 2], h[i4 * 4 + 3]);
  }
#pragma unroll
  for (int i = 0; i < 16; i++) acc[i] = b1_s[q * 16 + i];
#pragma unroll 2
  for (int k4 = 0; k4 < 16; k4++) {
    F4 hv; hv.v = hbuf4[g * 17 + k4];
#pragma unroll
    for (int c = 0; c < 4; c++) {
      float hk = hv.f[c];
      const float4* wrow = &w1T4[(k4 * 4 + c) * 16 + q * 4];
#pragma unroll
      for (int j4 = 0; j4 < 4; j4++) {
        float4 w = wrow[j4];
        acc[j4 * 4 + 0] = fmaf(hk, w.x, acc[j4 * 4 + 0]);
        acc[j4 * 4 + 1] = fmaf(hk, w.y, acc[j4 * 4 + 1]);
        acc[j4 * 4 + 2] = fmaf(hk, w.z, acc[j4 * 4 + 2]);
        acc[j4 * 4 + 3] = fmaf(hk, w.w, acc[j4 * 4 + 3]);
      }
    }
  }
  {
    float s = 0.f;
#pragma unroll
    for (int i = 0; i < 16; i++) s += acc[i];
    s += __shfl_xor(s, 1, 4); s += __shfl_xor(s, 2, 4);
    float mu = s * (1.f / 64.f);
    float vs = 0.f;
#pragma unroll
    for (int i = 0; i < 16; i++) { float dd = acc[i] - mu; vs += dd * dd; }
    vs += __shfl_xor(vs, 1, 4); vs += __shfl_xor(vs, 2, 4);
    float rs = rsqrtf(vs * (1.f / 64.f) + 1e-5f);
#pragma unroll
    for (int i = 0; i < 16; i++)
      h[i] = fmaxf((acc[i] - mu) * rs * l1w_s[q * 16 + i] + l1b_s[q * 16 + i], 0.f);
  }
#pragma unroll
  for (int i4 = 0; i4 < 4; i4++)
    hbuf4[g * 17 + q * 4 + i4] = make_float4(h[i4 * 4], h[i4 * 4 + 1], h[i4 * 4 + 2], h[i4 * 4 + 3]);
#pragma unroll
  for (int i = 0; i < 16; i++) acc[i] = b2_s[q * 16 + i];
#pragma unroll 2
  for (int k4 = 0; k4 < 16; k4++) {
    F4 hv; hv.v = hbuf4[g * 17 + k4];
#pragma unroll
    for (int c = 0; c < 4; c++) {
      float hk = hv.f[c];
      const float4* wrow = &w2T4[(k4 * 4 + c) * 16 + q * 4];
#pragma unroll
      for (int j4 = 0; j4 < 4; j4++) {
        float4 w = wrow[j4];
        acc[j4 * 4 + 0] = fmaf(hk, w.x, acc[j4 * 4 + 0]);
        acc[j4 * 4 + 1] = fmaf(hk, w.y, acc[j4 * 4 + 1]);
        acc[j4 * 4 + 2] = fmaf(hk, w.z, acc[j4 * 4 + 2]);
        acc[j4 * 4 + 3] = fmaf(hk, w.w, acc[j4 * 4 + 3]);
      }
    }
  }
  {
    float s = 0.f;
#pragma unroll
    for (int i = 0; i < 16; i++) s += acc[i];
    s += __shfl_xor(s, 1, 4); s += __shfl_xor(s, 2, 4);
    float mu = s * (1.f / 64.f);
    float vs = 0.f;
#pragma unroll
    for (int i = 0; i < 16; i++) { float dd = acc[i] - mu; vs += dd * dd; }
    vs += __shfl_xor(vs, 1, 4); vs += __shfl_xor(vs, 2, 4);
    float rs = rsqrtf(vs * (1.f / 64.f) + 1e-5f);
    float p = 0.f;
#pragma unroll
    for (int i = 0; i < 16; i++) {
      float hv2 = fmaxf((acc[i] - mu) * rs * l2w_s[q * 16 + i] + l2b_s[q * 16 + i], 0.f);
      p = fmaf(hv2, w3_s[q * 16 + i], p);
    }
    p += __shfl_xor(p, 1, 4); p += __shfl_xor(p, 2, 4);
    if (q == 0) outp[node] = 1.f / (1.f + __expf(-(p + bb3)));
  }
}

extern "C" void kernel_launch(void* const* d_in, const int* in_sizes, int n_in,
                              void* d_out, int out_size, void* d_ws, size_t ws_size,
                              hipStream_t stream) {
  const float* init_emb = (const float*)d_in[0];
  const int*   ei  = (const int*)d_in[1];
  const float* W1p = (const float*)d_in[2];
  const float* W1n = (const float*)d_in[3];
  const float* W1s = (const float*)d_in[4];
  const float* Wlp = (const float*)d_in[5];
  const float* Wln = (const float*)d_in[6];
  const float* Wls = (const float*)d_in[7];
  const float* lnw = (const float*)d_in[8];
  const float* lnb = (const float*)d_in[9];
  const float* gw  = (const float*)d_in[10];
  const float* gb  = (const float*)d_in[11];
  const float* pw  = (const float*)d_in[12];
  const float* pb  = (const float*)d_in[13];
  const float* w1  = (const float*)d_in[14];
  const float* b1  = (const float*)d_in[15];
  const float* l1w = (const float*)d_in[16];
  const float* l1b = (const float*)d_in[17];
  const float* w2  = (const float*)d_in[18];
  const float* b2  = (const float*)d_in[19];
  const float* l2w = (const float*)d_in[20];
  const float* l2b = (const float*)d_in[21];
  const float* w3  = (const float*)d_in[22];
  const float* b3  = (const float*)d_in[23];

  char* ws = (char*)d_ws;
  size_t off = 0;
  auto alloc = [&](size_t b) { void* p = ws + off; off = (off + b + 255) & ~(size_t)255; return p; };
  __hip_bfloat16* ypA = (__hip_bfloat16*)alloc(NODES * 32 * 2);
  __hip_bfloat16* ynA = (__hip_bfloat16*)alloc(NODES * 32 * 2);
  __hip_bfloat16* ypB = (__hip_bfloat16*)alloc(NODES * 32 * 2);
  __hip_bfloat16* ynB = (__hip_bfloat16*)alloc(NODES * 32 * 2);
  float*    ysel   = (float*)alloc(NODES * 32 * 4);
  float*    zbuf   = (float*)alloc(NODES * 32 * 4);
  unsigned* perm   = (unsigned*)alloc(EDGES * 4);
  int*      deg    = (int*)alloc(NODES * 4);
  int*      offs   = (int*)alloc((NODES + 1) * 4);
  int*      bsum   = (int*)alloc(128 * 4);
  int*      bucket_cnt    = (int*)alloc(NBUCK * 4);
  int*      bucket_base   = (int*)alloc(NBUCK * 4);
  int*      bucket_cursor = (int*)alloc(NBUCK * 4);
  // binned (6.4MB) aliases ypA+ynA: dead before k_lin64 writes them
  uint2*    binned = (uint2*)ypA;

  // ---- CSR build (two-pass bucketed scatter) ----
  hipMemsetAsync(deg, 0, NODES * 4, stream);
  hipMemsetAsync(bucket_cnt, 0, NBUCK * 4, stream);
  k_hist2<<<NBIN_BLOCKS, 256, 0, stream>>>(ei, deg, bucket_cnt);
  int nb = (NODES + 511) / 512;
  k_scan1<<<nb, 512, 0, stream>>>(deg, offs, bsum);
  k_scan2<<<1, 128, 0, stream>>>(bsum, nb);
  k_scan3<<<nb, 512, 0, stream>>>(offs, bsum);
  k_bscan<<<1, 256, 0, stream>>>(bucket_cnt, bucket_base, bucket_cursor);
  k_bin<<<NBIN_BLOCKS, 256, 0, stream>>>(ei, bucket_cursor, binned);
  k_scatter2<<<NBUCK, 256, 0, stream>>>(binned, bucket_base, bucket_cnt, offs, perm);

  const int G = NODES / 8;
  // layer 1 conv (K=64) -> yA
  k_lin64<<<G, 256, 0, stream>>>(init_emb, W1p, W1n, W1s, ypA, ynA, ysel);
  // L0: agg + ASFR + lin(Wl[0]); yA -> yB
  k_layer<1, 0, 1, 0><<<G, 256, 0, stream>>>((const unsigned short*)ypA, (const unsigned short*)ynA,
      ysel, perm, offs, zbuf, lnw, lnb, gw, gb, Wlp, Wln, Wls, ypB, ynB);
  // L1: agg no residual, write z, lin Wl[1]; yB -> yA
  k_layer<0, 0, 1, 1><<<G, 256, 0, stream>>>((const unsigned short*)ypB, (const unsigned short*)ynB,
      ysel, perm, offs, zbuf, nullptr, nullptr, nullptr, nullptr,
      Wlp + 1024, Wln + 1024, Wls + 1024, ypA, ynA);
  // L2..L7: agg + residual, write z, lin Wl[2..7]
  const __hip_bfloat16* yin_p = ypA; const __hip_bfloat16* yin_n = ynA;
  __hip_bfloat16* yout_p = ypB; __hip_bfloat16* yout_n = ynB;
  for (int i = 1; i < 7; i++) {
    k_layer<0, 1, 1, 1><<<G, 256, 0, stream>>>((const unsigned short*)yin_p, (const unsigned short*)yin_n,
        ysel, perm, offs, zbuf, nullptr, nullptr, nullptr, nullptr,
        Wlp + (i + 1) * 1024, Wln + (i + 1) * 1024, Wls + (i + 1) * 1024, yout_p, yout_n);
    const __hip_bfloat16* tp = yin_p; const __hip_bfloat16* tn = yin_n;
    yin_p = yout_p; yin_n = yout_n;
    yout_p = (__hip_bfloat16*)tp; yout_n = (__hip_bfloat16*)tn;
  }
  // L8: agg + residual, write z, no lin
  k_layer<0, 1, 0, 1><<<G, 256, 0, stream>>>((const unsigned short*)yin_p, (const unsigned short*)yin_n,
      ysel, perm, offs, zbuf, nullptr, nullptr, nullptr, nullptr,
      nullptr, nullptr, nullptr, nullptr, nullptr);

  // ---- fused head ----
  float* outz = (float*)d_out;
  float* outp = outz + (size_t)NODES * 64;
  k_mlp<<<(NODES * 4 + 255) / 256, 256, 0, stream>>>(zbuf, pw, pb, w1, b1, l1w, l1b,
                                                     w2, b2, l2w, l2b, w3, b3, outz, outp);
}